// Round 1
// baseline (2078.886 us; speedup 1.0000x reference)
//
#include <hip/hip_runtime.h>
#include <hip/hip_bf16.h>

#define DD 128

static __device__ __forceinline__ int gtid() {
    return blockIdx.x * blockDim.x + threadIdx.x;
}

// deg[i] = 1.0 (self loop)
__global__ void deg_init_kernel(float* __restrict__ deg, int n) {
    int i = gtid();
    if (i < n) deg[i] = 1.0f;
}

// deg[dst[e]] += 1
__global__ void deg_count_kernel(float* __restrict__ deg, const int* __restrict__ dst, int e) {
    int i = gtid();
    if (i < e) atomicAdd(&deg[dst[i]], 1.0f);
}

// in-place deg -> rsqrt(deg)
__global__ void dinv_kernel(float* __restrict__ d, int n) {
    int i = gtid();
    if (i < n) d[i] = rsqrtf(d[i]);
}

// hw[r,:] = hsrc[r,:] @ W (128x128), W staged transposed in LDS.
// 2 rows per wave, grid-stride over rows.
#define WT_LD 132
__global__ __launch_bounds__(256) void gemm128_kernel(
    const float* __restrict__ hsrc, int ld, const float* __restrict__ W,
    float* __restrict__ out, int nrows) {
    __shared__ float wt[128 * WT_LD];
    for (int i = threadIdx.x; i < 128 * 128; i += 256) {
        int k = i >> 7, j = i & 127;
        wt[j * WT_LD + k] = W[i];
    }
    __syncthreads();
    int lane = threadIdx.x & 63;
    int wv = threadIdx.x >> 6;
    const float* w0 = &wt[lane * WT_LD];
    const float* w1 = &wt[(lane + 64) * WT_LD];
    for (int base = blockIdx.x * 8 + wv * 2; base < nrows; base += gridDim.x * 8) {
        int r0 = base, r1 = base + 1;
        const float* h0p = hsrc + (size_t)r0 * ld;
        const float* h1p = (r1 < nrows) ? (hsrc + (size_t)r1 * ld) : h0p;
        float h0a = h0p[lane], h0b = h0p[lane + 64];
        float h1a = h1p[lane], h1b = h1p[lane + 64];
        float a00 = 0.f, a01 = 0.f, a10 = 0.f, a11 = 0.f;
#pragma unroll
        for (int kk = 0; kk < 64; kk += 4) {
            float4 wv0 = *(const float4*)(w0 + kk);
            float4 wv1 = *(const float4*)(w1 + kk);
#pragma unroll
            for (int u = 0; u < 4; ++u) {
                float we0 = (&wv0.x)[u];
                float we1 = (&wv1.x)[u];
                float hv0 = __shfl(h0a, kk + u);
                float hv1 = __shfl(h1a, kk + u);
                a00 = fmaf(hv0, we0, a00); a01 = fmaf(hv0, we1, a01);
                a10 = fmaf(hv1, we0, a10); a11 = fmaf(hv1, we1, a11);
            }
        }
#pragma unroll
        for (int kk = 0; kk < 64; kk += 4) {
            float4 wv0 = *(const float4*)(w0 + 64 + kk);
            float4 wv1 = *(const float4*)(w1 + 64 + kk);
#pragma unroll
            for (int u = 0; u < 4; ++u) {
                float we0 = (&wv0.x)[u];
                float we1 = (&wv1.x)[u];
                float hv0 = __shfl(h0b, kk + u);
                float hv1 = __shfl(h1b, kk + u);
                a00 = fmaf(hv0, we0, a00); a01 = fmaf(hv0, we1, a01);
                a10 = fmaf(hv1, we0, a10); a11 = fmaf(hv1, we1, a11);
            }
        }
        out[(size_t)r0 * 128 + lane] = a00;
        out[(size_t)r0 * 128 + 64 + lane] = a01;
        if (r1 < nrows) {
            out[(size_t)r1 * 128 + lane] = a10;
            out[(size_t)r1 * 128 + 64 + lane] = a11;
        }
    }
}

// one wave per edge: zsl[dst,:] += hw[src,:] * dinv[src]*dinv[dst]
__global__ __launch_bounds__(256) void scatter_kernel(
    const float* __restrict__ hw, const int* __restrict__ ei,
    const float* __restrict__ dinv, float* __restrict__ zsl, int e) {
    int gid = gtid();
    int edge = gid >> 6;
    if (edge >= e) return;
    int lane = gid & 63;
    int s = ei[edge];
    int d = ei[e + edge];
    float c = dinv[s] * dinv[d];
    const float* hr = hw + (size_t)s * 128;
    float* zr = zsl + (size_t)d * 384;
    atomicAdd(&zr[lane], hr[lane] * c);
    atomicAdd(&zr[lane + 64], hr[lane + 64] * c);
}

// zsl = relu(zsl + dinv^2*hw + bias)   (self-loop term folded in)
__global__ __launch_bounds__(256) void bias_relu_kernel(
    float* __restrict__ zsl, const float* __restrict__ hw,
    const float* __restrict__ dinv, const float* __restrict__ bias, int n) {
    int gid = gtid();
    if (gid >= n * 128) return;
    int r = gid >> 7, d = gid & 127;
    float di = dinv[r];
    float v = zsl[(size_t)r * 384 + d] + di * di * hw[(size_t)r * 128 + d] + bias[d];
    zsl[(size_t)r * 384 + d] = fmaxf(v, 0.0f);
}

// one wave per pair; block-reduce; atomicAdd scaled term into out[0]
__global__ __launch_bounds__(256) void loss_kernel(
    const float* __restrict__ z, const int* __restrict__ pos, const int* __restrict__ neg,
    const float* __restrict__ pw, const float* __restrict__ pb,
    float* __restrict__ out, int p, float inv_total) {
    __shared__ float red[4];
    int gid = gtid();
    int wave = gid >> 6;
    int lane = gid & 63;
    int wib = threadIdx.x >> 6;
    float term = 0.0f;
    if (wave < 2 * p) {
        bool isneg = (wave >= p);
        const int* pr = isneg ? neg : pos;
        int idx = isneg ? (wave - p) : wave;
        int a = pr[idx];
        int b = pr[p + idx];
        const float* za = z + (size_t)a * 384;
        const float* zb = z + (size_t)b * 384;
        float acc = 0.0f;
#pragma unroll
        for (int i = 0; i < 6; ++i) {
            int d = lane + i * 64;
            acc = fmaf(za[d] * zb[d], pw[d], acc);
        }
#pragma unroll
        for (int off = 32; off > 0; off >>= 1) acc += __shfl_xor(acc, off);
        float logit = acc + pb[0];
        if (isneg) logit = -logit;
        float t = -logit;  // -log sigmoid(logit) = softplus(-logit)
        term = (fmaxf(t, 0.0f) + log1pf(expf(-fabsf(t)))) * inv_total;
    }
    if (lane == 0) red[wib] = term;
    __syncthreads();
    if (threadIdx.x == 0) atomicAdd(out, red[0] + red[1] + red[2] + red[3]);
}

extern "C" void kernel_launch(void* const* d_in, const int* in_sizes, int n_in,
                              void* d_out, int out_size, void* d_ws, size_t ws_size,
                              hipStream_t stream) {
    const float* x      = (const float*)d_in[0];
    const int*   ei     = (const int*)d_in[1];
    const int*   pos    = (const int*)d_in[2];
    const int*   neg    = (const int*)d_in[3];
    const float* gcn_w  = (const float*)d_in[4];
    const float* gcn_b  = (const float*)d_in[5];
    const float* pred_w = (const float*)d_in[6];
    const float* pred_b = (const float*)d_in[7];
    float* out = (float*)d_out;

    const int n = in_sizes[0] / DD;     // 50000
    const int e = in_sizes[1] / 2;      // 640000
    const int p = in_sizes[2] / 2;      // 100000

    // workspace layout: dinv[n] | hw[n*128] | z[n*384]
    char* ws = (char*)d_ws;
    size_t off = 0;
    float* dinv = (float*)(ws + off); off += ((size_t)n * 4 + 255) & ~(size_t)255;
    float* hw   = (float*)(ws + off); off += ((size_t)n * 128 * 4 + 255) & ~(size_t)255;
    float* z    = (float*)(ws + off); off += ((size_t)n * 384 * 4 + 255) & ~(size_t)255;
    (void)ws_size;

    hipMemsetAsync(z, 0, (size_t)n * 384 * 4, stream);
    hipMemsetAsync(d_out, 0, (size_t)out_size * 4, stream);

    deg_init_kernel<<<(n + 255) / 256, 256, 0, stream>>>(dinv, n);
    deg_count_kernel<<<(e + 255) / 256, 256, 0, stream>>>(dinv, ei + e, e);
    dinv_kernel<<<(n + 255) / 256, 256, 0, stream>>>(dinv, n);

    for (int l = 0; l < 3; ++l) {
        const float* hsrc = (l == 0) ? x : (z + (size_t)(l - 1) * 128);
        int ld = (l == 0) ? 128 : 384;
        gemm128_kernel<<<1024, 256, 0, stream>>>(hsrc, ld, gcn_w + (size_t)l * 128 * 128, hw, n);
        scatter_kernel<<<(e * 64 + 255) / 256, 256, 0, stream>>>(hw, ei, dinv, z + (size_t)l * 128, e);
        bias_relu_kernel<<<((size_t)n * 128 + 255) / 256, 256, 0, stream>>>(
            z + (size_t)l * 128, hw, dinv, gcn_b + (size_t)l * 128, n);
    }

    float inv_total = 1.0f / (2.0f * (float)p);
    loss_kernel<<<(2 * p + 3) / 4, 256, 0, stream>>>(z, pos, neg, pred_w, pred_b, out, p, inv_total);
}

// Round 2
// 941.597 us; speedup vs baseline: 2.2078x; 2.2078x over previous
//
#include <hip/hip_runtime.h>
#include <hip/hip_bf16.h>

#define DD 128

static __device__ __forceinline__ int gtid() {
    return blockIdx.x * blockDim.x + threadIdx.x;
}

static __device__ __forceinline__ float bf2f(ushort u) {
    return __uint_as_float(((unsigned int)u) << 16);
}

// ---------- degree / CSR build ----------

__global__ void count_kernel(int* __restrict__ counts, const int* __restrict__ dst, int e) {
    int i = gtid();
    if (i < e) atomicAdd(&counts[dst[i]], 1);
}

__global__ void dinv_kernel(float* __restrict__ dinv, const int* __restrict__ counts, int n) {
    int i = gtid();
    if (i < n) dinv[i] = rsqrtf(1.0f + (float)counts[i]);
}

// block-level exclusive scan (Hillis-Steele in LDS), partial[b] = block total
__global__ __launch_bounds__(256) void scan_blocks(const int* __restrict__ counts,
                                                   int* __restrict__ rowptr,
                                                   int* __restrict__ partial, int n) {
    __shared__ int s[256];
    int i = blockIdx.x * 256 + threadIdx.x;
    int v = (i < n) ? counts[i] : 0;
    s[threadIdx.x] = v;
    __syncthreads();
    for (int off = 1; off < 256; off <<= 1) {
        int t = (threadIdx.x >= off) ? s[threadIdx.x - off] : 0;
        __syncthreads();
        s[threadIdx.x] += t;
        __syncthreads();
    }
    if (i < n) rowptr[i] = s[threadIdx.x] - v;  // exclusive, pre-offset
    if (threadIdx.x == 255) partial[blockIdx.x] = s[255];
}

// single-block scan of partials (nb <= 256)
__global__ __launch_bounds__(256) void scan_partials(int* __restrict__ partial,
                                                     int* __restrict__ partial2, int nb) {
    __shared__ int s[256];
    int v = (threadIdx.x < nb) ? partial[threadIdx.x] : 0;
    s[threadIdx.x] = v;
    __syncthreads();
    for (int off = 1; off < 256; off <<= 1) {
        int t = (threadIdx.x >= off) ? s[threadIdx.x - off] : 0;
        __syncthreads();
        s[threadIdx.x] += t;
        __syncthreads();
    }
    partial2[threadIdx.x] = s[threadIdx.x] - v;  // exclusive
}

__global__ __launch_bounds__(256) void add_offsets(int* __restrict__ rowptr,
                                                   int* __restrict__ cursor,
                                                   const int* __restrict__ partial2,
                                                   int n, int e) {
    int i = blockIdx.x * 256 + threadIdx.x;
    if (i < n) {
        int r = rowptr[i] + partial2[blockIdx.x];
        rowptr[i] = r;
        cursor[i] = r;
        if (i == n - 1) rowptr[n] = e;
    }
}

__global__ void fill_kernel(const int* __restrict__ ei, const float* __restrict__ dinv,
                            int* __restrict__ cursor, int* __restrict__ csr_src,
                            float* __restrict__ csr_coef, int e) {
    int i = gtid();
    if (i >= e) return;
    int s = ei[i];
    int d = ei[e + i];
    float c = dinv[s] * dinv[d];
    int pos = atomicAdd(&cursor[d], 1);
    csr_src[pos] = s;
    csr_coef[pos] = c;
}

// ---------- x -> bf16 ----------
__global__ void cvt_kernel(const float* __restrict__ x, __hip_bfloat16* __restrict__ xh, size_t m) {
    size_t i = (size_t)blockIdx.x * blockDim.x + threadIdx.x;
    if (i < m) xh[i] = __float2bfloat16(x[i]);
}

// ---------- GEMM: hw[r,:] = h[r,:] @ W (128x128), bf16 in/out, f32 math ----------
#define WT_LD 132
__global__ __launch_bounds__(256) void gemm128_kernel(
    const __hip_bfloat16* __restrict__ hsrc, int ld, const float* __restrict__ W,
    __hip_bfloat16* __restrict__ out, int nrows) {
    __shared__ float wt[128 * WT_LD];
    for (int i = threadIdx.x; i < 128 * 128; i += 256) {
        int k = i >> 7, j = i & 127;
        wt[j * WT_LD + k] = W[i];
    }
    __syncthreads();
    int lane = threadIdx.x & 63;
    int wv = threadIdx.x >> 6;
    const float* w0 = &wt[lane * WT_LD];
    const float* w1 = &wt[(lane + 64) * WT_LD];
    for (int base = blockIdx.x * 8 + wv * 2; base < nrows; base += gridDim.x * 8) {
        int r0 = base, r1 = base + 1;
        const __hip_bfloat16* h0p = hsrc + (size_t)r0 * ld;
        const __hip_bfloat16* h1p = (r1 < nrows) ? (hsrc + (size_t)r1 * ld) : h0p;
        float h0a = __bfloat162float(h0p[lane]), h0b = __bfloat162float(h0p[lane + 64]);
        float h1a = __bfloat162float(h1p[lane]), h1b = __bfloat162float(h1p[lane + 64]);
        float a00 = 0.f, a01 = 0.f, a10 = 0.f, a11 = 0.f;
#pragma unroll
        for (int kk = 0; kk < 64; kk += 4) {
            float4 wv0 = *(const float4*)(w0 + kk);
            float4 wv1 = *(const float4*)(w1 + kk);
#pragma unroll
            for (int u = 0; u < 4; ++u) {
                float we0 = (&wv0.x)[u];
                float we1 = (&wv1.x)[u];
                float hv0 = __shfl(h0a, kk + u);
                float hv1 = __shfl(h1a, kk + u);
                a00 = fmaf(hv0, we0, a00); a01 = fmaf(hv0, we1, a01);
                a10 = fmaf(hv1, we0, a10); a11 = fmaf(hv1, we1, a11);
            }
        }
#pragma unroll
        for (int kk = 0; kk < 64; kk += 4) {
            float4 wv0 = *(const float4*)(w0 + 64 + kk);
            float4 wv1 = *(const float4*)(w1 + 64 + kk);
#pragma unroll
            for (int u = 0; u < 4; ++u) {
                float we0 = (&wv0.x)[u];
                float we1 = (&wv1.x)[u];
                float hv0 = __shfl(h0b, kk + u);
                float hv1 = __shfl(h1b, kk + u);
                a00 = fmaf(hv0, we0, a00); a01 = fmaf(hv0, we1, a01);
                a10 = fmaf(hv1, we0, a10); a11 = fmaf(hv1, we1, a11);
            }
        }
        out[(size_t)r0 * 128 + lane] = __float2bfloat16(a00);
        out[(size_t)r0 * 128 + 64 + lane] = __float2bfloat16(a01);
        if (r1 < nrows) {
            out[(size_t)r1 * 128 + lane] = __float2bfloat16(a10);
            out[(size_t)r1 * 128 + 64 + lane] = __float2bfloat16(a11);
        }
    }
}

// ---------- fused aggregate + self-loop + bias + relu ----------
// one wave per dst row; edge metadata loaded 64-at-a-time and broadcast via shfl
__global__ __launch_bounds__(256) void aggregate_kernel(
    const __hip_bfloat16* __restrict__ hw, const int* __restrict__ rowptr,
    const int* __restrict__ csr_src, const float* __restrict__ csr_coef,
    const float* __restrict__ dinv, const float* __restrict__ bias,
    __hip_bfloat16* __restrict__ zsl, int n) {
    int gid = gtid();
    int row = gid >> 6;
    if (row >= n) return;
    int lane = gid & 63;
    int j0 = rowptr[row], j1 = rowptr[row + 1];
    float a0 = 0.f, a1 = 0.f;
    for (int base = j0; base < j1; base += 64) {
        int jmax = j1 - base;
        int sv = 0; float cv = 0.f;
        if (lane < jmax) {
            sv = csr_src[base + lane];
            cv = csr_coef[base + lane];
        }
        int kmax = (jmax < 64) ? jmax : 64;
        for (int k = 0; k < kmax; ++k) {
            int s = __shfl(sv, k);
            float c = __shfl(cv, k);
            const __hip_bfloat16* hr = hw + (size_t)s * 128;
            a0 = fmaf(c, __bfloat162float(hr[lane]), a0);
            a1 = fmaf(c, __bfloat162float(hr[lane + 64]), a1);
        }
    }
    float di = dinv[row];
    float d2 = di * di;
    const __hip_bfloat16* hs = hw + (size_t)row * 128;
    a0 = fmaf(d2, __bfloat162float(hs[lane]), a0) + bias[lane];
    a1 = fmaf(d2, __bfloat162float(hs[lane + 64]), a1) + bias[lane + 64];
    zsl[(size_t)row * 384 + lane] = __float2bfloat16(fmaxf(a0, 0.f));
    zsl[(size_t)row * 384 + lane + 64] = __float2bfloat16(fmaxf(a1, 0.f));
}

// ---------- loss: 16 lanes per pair, uint4 (8x bf16) loads ----------
__global__ __launch_bounds__(256) void loss_kernel(
    const ushort* __restrict__ zh, const int* __restrict__ pos, const int* __restrict__ neg,
    const float* __restrict__ pw, const float* __restrict__ pb,
    float* __restrict__ out, int p, float inv_total) {
    __shared__ float pwl[384];
    __shared__ float red[16];
    for (int i = threadIdx.x; i < 384; i += 256) pwl[i] = pw[i];
    if (threadIdx.x < 16) red[threadIdx.x] = 0.f;
    __syncthreads();
    int sub = threadIdx.x & 15;
    int pairIdx = blockIdx.x * 16 + (threadIdx.x >> 4);
    if (pairIdx < 2 * p) {
        bool isneg = (pairIdx >= p);
        const int* pr = isneg ? neg : pos;
        int idx = isneg ? (pairIdx - p) : pairIdx;
        int a = pr[idx];
        int b = pr[p + idx];
        const uint4* za = (const uint4*)(zh + (size_t)a * 384);
        const uint4* zb = (const uint4*)(zh + (size_t)b * 384);
        float acc = 0.f;
#pragma unroll
        for (int j = 0; j < 3; ++j) {
            uint4 va = za[sub + j * 16];
            uint4 vb = zb[sub + j * 16];
            int d0 = (sub + j * 16) * 8;
            const unsigned int* ua = (const unsigned int*)&va;
            const unsigned int* ub = (const unsigned int*)&vb;
#pragma unroll
            for (int q = 0; q < 4; ++q) {
                float fa0 = __uint_as_float(ua[q] << 16);
                float fa1 = __uint_as_float(ua[q] & 0xffff0000u);
                float fb0 = __uint_as_float(ub[q] << 16);
                float fb1 = __uint_as_float(ub[q] & 0xffff0000u);
                acc = fmaf(fa0 * fb0, pwl[d0 + 2 * q], acc);
                acc = fmaf(fa1 * fb1, pwl[d0 + 2 * q + 1], acc);
            }
        }
#pragma unroll
        for (int off = 1; off < 16; off <<= 1) acc += __shfl_xor(acc, off);
        if (sub == 0) {
            float logit = acc + pb[0];
            if (isneg) logit = -logit;
            float t = -logit;  // softplus(-logit) = -log sigmoid(logit)
            red[threadIdx.x >> 4] = (fmaxf(t, 0.f) + log1pf(expf(-fabsf(t)))) * inv_total;
        }
    }
    __syncthreads();
    if (threadIdx.x == 0) {
        float s = 0.f;
#pragma unroll
        for (int i = 0; i < 16; ++i) s += red[i];
        atomicAdd(out, s);
    }
}

extern "C" void kernel_launch(void* const* d_in, const int* in_sizes, int n_in,
                              void* d_out, int out_size, void* d_ws, size_t ws_size,
                              hipStream_t stream) {
    const float* x      = (const float*)d_in[0];
    const int*   ei     = (const int*)d_in[1];
    const int*   pos    = (const int*)d_in[2];
    const int*   neg    = (const int*)d_in[3];
    const float* gcn_w  = (const float*)d_in[4];
    const float* gcn_b  = (const float*)d_in[5];
    const float* pred_w = (const float*)d_in[6];
    const float* pred_b = (const float*)d_in[7];
    float* out = (float*)d_out;

    const int n = in_sizes[0] / DD;     // 50000
    const int e = in_sizes[1] / 2;      // 640000
    const int p = in_sizes[2] / 2;      // 100000
    const int nb = (n + 255) / 256;     // 196

    // workspace layout
    char* ws = (char*)d_ws;
    size_t off = 0;
    auto alloc = [&](size_t bytes) {
        void* ptr = ws + off;
        off += (bytes + 255) & ~(size_t)255;
        return ptr;
    };
    float* dinv      = (float*)alloc((size_t)n * 4);
    int*   counts    = (int*)alloc((size_t)n * 4);
    int*   rowptr    = (int*)alloc((size_t)(n + 1) * 4);
    int*   cursor    = (int*)alloc((size_t)n * 4);
    int*   partial   = (int*)alloc(256 * 4);
    int*   partial2  = (int*)alloc(256 * 4);
    int*   csr_src   = (int*)alloc((size_t)e * 4);
    float* csr_coef  = (float*)alloc((size_t)e * 4);
    __hip_bfloat16* xh = (__hip_bfloat16*)alloc((size_t)n * 128 * 2);
    __hip_bfloat16* hw = (__hip_bfloat16*)alloc((size_t)n * 128 * 2);
    __hip_bfloat16* zh = (__hip_bfloat16*)alloc((size_t)n * 384 * 2);
    (void)ws_size;

    hipMemsetAsync(counts, 0, (size_t)n * 4, stream);
    hipMemsetAsync(d_out, 0, (size_t)out_size * 4, stream);

    // CSR build
    count_kernel<<<(e + 255) / 256, 256, 0, stream>>>(counts, ei + e, e);
    dinv_kernel<<<nb, 256, 0, stream>>>(dinv, counts, n);
    scan_blocks<<<nb, 256, 0, stream>>>(counts, rowptr, partial, n);
    scan_partials<<<1, 256, 0, stream>>>(partial, partial2, nb);
    add_offsets<<<nb, 256, 0, stream>>>(rowptr, cursor, partial2, n, e);
    fill_kernel<<<(e + 255) / 256, 256, 0, stream>>>(ei, dinv, cursor, csr_src, csr_coef, e);

    // x -> bf16
    cvt_kernel<<<(int)(((size_t)n * 128 + 255) / 256), 256, 0, stream>>>(x, xh, (size_t)n * 128);

    for (int l = 0; l < 3; ++l) {
        const __hip_bfloat16* hsrc = (l == 0) ? xh : (zh + (size_t)(l - 1) * 128);
        int ld = (l == 0) ? 128 : 384;
        gemm128_kernel<<<1024, 256, 0, stream>>>(hsrc, ld, gcn_w + (size_t)l * 128 * 128, hw, n);
        aggregate_kernel<<<(n * 64 + 255) / 256, 256, 0, stream>>>(
            hw, rowptr, csr_src, csr_coef, dinv, gcn_b + (size_t)l * 128, zh + (size_t)l * 128, n);
    }

    float inv_total = 1.0f / (2.0f * (float)p);
    loss_kernel<<<(2 * p + 15) / 16, 256, 0, stream>>>(
        (const ushort*)zh, pos, neg, pred_w, pred_b, out, p, inv_total);
}

// Round 3
// 452.394 us; speedup vs baseline: 4.5953x; 2.0814x over previous
//
#include <hip/hip_runtime.h>
#include <hip/hip_bf16.h>

#define DD 128

typedef __attribute__((ext_vector_type(8))) short short8;
typedef __attribute__((ext_vector_type(4))) float f32x4;

static __device__ __forceinline__ int gtid() {
    return blockIdx.x * blockDim.x + threadIdx.x;
}

static __device__ __forceinline__ ushort f2bfu(float f) {
    __hip_bfloat16 h = __float2bfloat16(f);
    return *reinterpret_cast<ushort*>(&h);
}

// ---------- degree / CSR build ----------

__global__ void count_kernel(int* __restrict__ counts, const int* __restrict__ dst, int e) {
    int i = gtid();
    if (i < e) atomicAdd(&counts[dst[i]], 1);
}

__global__ void dinv_kernel(float* __restrict__ dinv, const int* __restrict__ counts, int n) {
    int i = gtid();
    if (i < n) dinv[i] = rsqrtf(1.0f + (float)counts[i]);
}

// block-level exclusive scan (Hillis-Steele in LDS), partial[b] = block total
__global__ __launch_bounds__(256) void scan_blocks(const int* __restrict__ counts,
                                                   int* __restrict__ rowptr,
                                                   int* __restrict__ partial, int n) {
    __shared__ int s[256];
    int i = blockIdx.x * 256 + threadIdx.x;
    int v = (i < n) ? counts[i] : 0;
    s[threadIdx.x] = v;
    __syncthreads();
    for (int off = 1; off < 256; off <<= 1) {
        int t = (threadIdx.x >= off) ? s[threadIdx.x - off] : 0;
        __syncthreads();
        s[threadIdx.x] += t;
        __syncthreads();
    }
    if (i < n) rowptr[i] = s[threadIdx.x] - v;  // exclusive, pre-offset
    if (threadIdx.x == 255) partial[blockIdx.x] = s[255];
}

// single-block scan of partials (nb <= 256)
__global__ __launch_bounds__(256) void scan_partials(int* __restrict__ partial,
                                                     int* __restrict__ partial2, int nb) {
    __shared__ int s[256];
    int v = (threadIdx.x < nb) ? partial[threadIdx.x] : 0;
    s[threadIdx.x] = v;
    __syncthreads();
    for (int off = 1; off < 256; off <<= 1) {
        int t = (threadIdx.x >= off) ? s[threadIdx.x - off] : 0;
        __syncthreads();
        s[threadIdx.x] += t;
        __syncthreads();
    }
    partial2[threadIdx.x] = s[threadIdx.x] - v;  // exclusive
}

__global__ __launch_bounds__(256) void add_offsets(int* __restrict__ rowptr,
                                                   int* __restrict__ cursor,
                                                   const int* __restrict__ partial2,
                                                   int n, int e) {
    int i = blockIdx.x * 256 + threadIdx.x;
    if (i < n) {
        int r = rowptr[i] + partial2[blockIdx.x];
        rowptr[i] = r;
        cursor[i] = r;
        if (i == n - 1) rowptr[n] = e;
    }
}

__global__ void fill_kernel(const int* __restrict__ ei, const float* __restrict__ dinv,
                            int* __restrict__ cursor, int* __restrict__ csr_src,
                            float* __restrict__ csr_coef, int e) {
    int i = gtid();
    if (i >= e) return;
    int s = ei[i];
    int d = ei[e + i];
    float c = dinv[s] * dinv[d];
    int pos = atomicAdd(&cursor[d], 1);
    csr_src[pos] = s;
    csr_coef[pos] = c;
}

// ---------- x -> bf16 ----------
__global__ void cvt_kernel(const float* __restrict__ x, __hip_bfloat16* __restrict__ xh, size_t m) {
    size_t i = (size_t)blockIdx.x * blockDim.x + threadIdx.x;
    if (i < m) xh[i] = __float2bfloat16(x[i]);
}

// ---------- W -> bf16 MFMA B-fragment order ----------
// frag index: ((l*32 + s*8 + c)*64 + lane), each frag elem j (0..7):
//   B[k = s*32 + (lane>>4)*8 + j][col = c*16 + (lane&15)]
__global__ __launch_bounds__(256) void wpack_kernel(const float* __restrict__ gcn_w,
                                                    ushort* __restrict__ wfrag) {
    int tid = blockIdx.x * 256 + threadIdx.x;  // 0 .. 6143
    if (tid >= 3 * 4 * 8 * 64) return;
    int lane = tid & 63;
    int c = (tid >> 6) & 7;
    int s = (tid >> 9) & 3;
    int l = tid >> 11;
    const float* W = gcn_w + (size_t)l * 128 * 128;
    int col = c * 16 + (lane & 15);
    int k0 = s * 32 + (lane >> 4) * 8;
    ushort u[8];
#pragma unroll
    for (int j = 0; j < 8; ++j) {
        u[j] = f2bfu(W[(size_t)(k0 + j) * 128 + col]);
    }
    *reinterpret_cast<uint4*>(wfrag + (size_t)tid * 8) = *reinterpret_cast<const uint4*>(u);
}

// ---------- MFMA GEMM: out[r,:] = hsrc[r,:] @ W, bf16 in/out, f32 accum ----------
// 4 waves/block; wave w owns cols [32w, 32w+32); all waves share each 16-row A tile.
// B fragments live in registers for the whole kernel.
__global__ __launch_bounds__(256) void gemm_mfma_kernel(
    const ushort* __restrict__ hsrc, int ld, const ushort* __restrict__ wfrag,
    ushort* __restrict__ out, int ntiles) {
    int lane = threadIdx.x & 63;
    int wv = threadIdx.x >> 6;
    short8 b0[4], b1[4];
    int c0 = wv * 2;
#pragma unroll
    for (int s = 0; s < 4; ++s) {
        b0[s] = *reinterpret_cast<const short8*>(wfrag + ((size_t)(s * 8 + c0) * 64 + lane) * 8);
        b1[s] = *reinterpret_cast<const short8*>(wfrag + ((size_t)(s * 8 + c0 + 1) * 64 + lane) * 8);
    }
    int rlo = lane & 15;
    int kg = lane >> 4;
    for (int rt = blockIdx.x; rt < ntiles; rt += gridDim.x) {
        const ushort* ap = hsrc + (size_t)(rt * 16 + rlo) * ld + kg * 8;
        short8 a0 = *reinterpret_cast<const short8*>(ap);
        short8 a1 = *reinterpret_cast<const short8*>(ap + 32);
        short8 a2 = *reinterpret_cast<const short8*>(ap + 64);
        short8 a3 = *reinterpret_cast<const short8*>(ap + 96);
        f32x4 acc0 = {0.f, 0.f, 0.f, 0.f};
        f32x4 acc1 = {0.f, 0.f, 0.f, 0.f};
        acc0 = __builtin_amdgcn_mfma_f32_16x16x32_bf16(a0, b0[0], acc0, 0, 0, 0);
        acc1 = __builtin_amdgcn_mfma_f32_16x16x32_bf16(a0, b1[0], acc1, 0, 0, 0);
        acc0 = __builtin_amdgcn_mfma_f32_16x16x32_bf16(a1, b0[1], acc0, 0, 0, 0);
        acc1 = __builtin_amdgcn_mfma_f32_16x16x32_bf16(a1, b1[1], acc1, 0, 0, 0);
        acc0 = __builtin_amdgcn_mfma_f32_16x16x32_bf16(a2, b0[2], acc0, 0, 0, 0);
        acc1 = __builtin_amdgcn_mfma_f32_16x16x32_bf16(a2, b1[2], acc1, 0, 0, 0);
        acc0 = __builtin_amdgcn_mfma_f32_16x16x32_bf16(a3, b0[3], acc0, 0, 0, 0);
        acc1 = __builtin_amdgcn_mfma_f32_16x16x32_bf16(a3, b1[3], acc1, 0, 0, 0);
        // C/D: col = lane&15, row = (lane>>4)*4 + r  [m89]
        int row0 = rt * 16 + kg * 4;
        ushort* orow = out + (size_t)row0 * 128 + wv * 32 + rlo;
#pragma unroll
        for (int r = 0; r < 4; ++r) {
            orow[(size_t)r * 128] = f2bfu(acc0[r]);
            orow[(size_t)r * 128 + 16] = f2bfu(acc1[r]);
        }
    }
}

// ---------- fused aggregate + self-loop + bias + relu ----------
// one wave per dst row; edge metadata loaded 64-at-a-time and broadcast via shfl
__global__ __launch_bounds__(256) void aggregate_kernel(
    const __hip_bfloat16* __restrict__ hw, const int* __restrict__ rowptr,
    const int* __restrict__ csr_src, const float* __restrict__ csr_coef,
    const float* __restrict__ dinv, const float* __restrict__ bias,
    __hip_bfloat16* __restrict__ zsl, int n) {
    int gid = gtid();
    int row = gid >> 6;
    if (row >= n) return;
    int lane = gid & 63;
    int j0 = rowptr[row], j1 = rowptr[row + 1];
    float a0 = 0.f, a1 = 0.f;
    for (int base = j0; base < j1; base += 64) {
        int jmax = j1 - base;
        int sv = 0; float cv = 0.f;
        if (lane < jmax) {
            sv = csr_src[base + lane];
            cv = csr_coef[base + lane];
        }
        int kmax = (jmax < 64) ? jmax : 64;
        for (int k = 0; k < kmax; ++k) {
            int s = __shfl(sv, k);
            float c = __shfl(cv, k);
            const __hip_bfloat16* hr = hw + (size_t)s * 128;
            a0 = fmaf(c, __bfloat162float(hr[lane]), a0);
            a1 = fmaf(c, __bfloat162float(hr[lane + 64]), a1);
        }
    }
    float di = dinv[row];
    float d2 = di * di;
    const __hip_bfloat16* hs = hw + (size_t)row * 128;
    a0 = fmaf(d2, __bfloat162float(hs[lane]), a0) + bias[lane];
    a1 = fmaf(d2, __bfloat162float(hs[lane + 64]), a1) + bias[lane + 64];
    zsl[(size_t)row * 384 + lane] = __float2bfloat16(fmaxf(a0, 0.f));
    zsl[(size_t)row * 384 + lane + 64] = __float2bfloat16(fmaxf(a1, 0.f));
}

// ---------- loss: 16 lanes per pair, uint4 (8x bf16) loads ----------
__global__ __launch_bounds__(256) void loss_kernel(
    const ushort* __restrict__ zh, const int* __restrict__ pos, const int* __restrict__ neg,
    const float* __restrict__ pw, const float* __restrict__ pb,
    float* __restrict__ out, int p, float inv_total) {
    __shared__ float pwl[384];
    __shared__ float red[16];
    for (int i = threadIdx.x; i < 384; i += 256) pwl[i] = pw[i];
    if (threadIdx.x < 16) red[threadIdx.x] = 0.f;
    __syncthreads();
    int sub = threadIdx.x & 15;
    int pairIdx = blockIdx.x * 16 + (threadIdx.x >> 4);
    if (pairIdx < 2 * p) {
        bool isneg = (pairIdx >= p);
        const int* pr = isneg ? neg : pos;
        int idx = isneg ? (pairIdx - p) : pairIdx;
        int a = pr[idx];
        int b = pr[p + idx];
        const uint4* za = (const uint4*)(zh + (size_t)a * 384);
        const uint4* zb = (const uint4*)(zh + (size_t)b * 384);
        float acc = 0.f;
#pragma unroll
        for (int j = 0; j < 3; ++j) {
            uint4 va = za[sub + j * 16];
            uint4 vb = zb[sub + j * 16];
            int d0 = (sub + j * 16) * 8;
            const unsigned int* ua = (const unsigned int*)&va;
            const unsigned int* ub = (const unsigned int*)&vb;
#pragma unroll
            for (int q = 0; q < 4; ++q) {
                float fa0 = __uint_as_float(ua[q] << 16);
                float fa1 = __uint_as_float(ua[q] & 0xffff0000u);
                float fb0 = __uint_as_float(ub[q] << 16);
                float fb1 = __uint_as_float(ub[q] & 0xffff0000u);
                acc = fmaf(fa0 * fb0, pwl[d0 + 2 * q], acc);
                acc = fmaf(fa1 * fb1, pwl[d0 + 2 * q + 1], acc);
            }
        }
#pragma unroll
        for (int off = 1; off < 16; off <<= 1) acc += __shfl_xor(acc, off);
        if (sub == 0) {
            float logit = acc + pb[0];
            if (isneg) logit = -logit;
            float t = -logit;  // softplus(-logit) = -log sigmoid(logit)
            red[threadIdx.x >> 4] = (fmaxf(t, 0.f) + log1pf(expf(-fabsf(t)))) * inv_total;
        }
    }
    __syncthreads();
    if (threadIdx.x == 0) {
        float s = 0.f;
#pragma unroll
        for (int i = 0; i < 16; ++i) s += red[i];
        atomicAdd(out, s);
    }
}

extern "C" void kernel_launch(void* const* d_in, const int* in_sizes, int n_in,
                              void* d_out, int out_size, void* d_ws, size_t ws_size,
                              hipStream_t stream) {
    const float* x      = (const float*)d_in[0];
    const int*   ei     = (const int*)d_in[1];
    const int*   pos    = (const int*)d_in[2];
    const int*   neg    = (const int*)d_in[3];
    const float* gcn_w  = (const float*)d_in[4];
    const float* gcn_b  = (const float*)d_in[5];
    const float* pred_w = (const float*)d_in[6];
    const float* pred_b = (const float*)d_in[7];
    float* out = (float*)d_out;

    const int n = in_sizes[0] / DD;     // 50000
    const int e = in_sizes[1] / 2;      // 640000
    const int p = in_sizes[2] / 2;      // 100000
    const int nb = (n + 255) / 256;     // 196

    // workspace layout
    char* ws = (char*)d_ws;
    size_t off = 0;
    auto alloc = [&](size_t bytes) {
        void* ptr = ws + off;
        off += (bytes + 255) & ~(size_t)255;
        return ptr;
    };
    float* dinv      = (float*)alloc((size_t)n * 4);
    int*   counts    = (int*)alloc((size_t)n * 4);
    int*   rowptr    = (int*)alloc((size_t)(n + 1) * 4);
    int*   cursor    = (int*)alloc((size_t)n * 4);
    int*   partial   = (int*)alloc(256 * 4);
    int*   partial2  = (int*)alloc(256 * 4);
    int*   csr_src   = (int*)alloc((size_t)e * 4);
    float* csr_coef  = (float*)alloc((size_t)e * 4);
    ushort* wfrag    = (ushort*)alloc((size_t)3 * 2048 * 8 * 2);
    __hip_bfloat16* xh = (__hip_bfloat16*)alloc((size_t)n * 128 * 2);
    __hip_bfloat16* hw = (__hip_bfloat16*)alloc((size_t)n * 128 * 2);
    __hip_bfloat16* zh = (__hip_bfloat16*)alloc((size_t)n * 384 * 2);
    (void)ws_size;

    hipMemsetAsync(counts, 0, (size_t)n * 4, stream);
    hipMemsetAsync(d_out, 0, (size_t)out_size * 4, stream);

    // CSR build
    count_kernel<<<(e + 255) / 256, 256, 0, stream>>>(counts, ei + e, e);
    dinv_kernel<<<nb, 256, 0, stream>>>(dinv, counts, n);
    scan_blocks<<<nb, 256, 0, stream>>>(counts, rowptr, partial, n);
    scan_partials<<<1, 256, 0, stream>>>(partial, partial2, nb);
    add_offsets<<<nb, 256, 0, stream>>>(rowptr, cursor, partial2, n, e);
    fill_kernel<<<(e + 255) / 256, 256, 0, stream>>>(ei, dinv, cursor, csr_src, csr_coef, e);

    // x -> bf16, W -> fragment-packed bf16
    cvt_kernel<<<(int)(((size_t)n * 128 + 255) / 256), 256, 0, stream>>>(x, xh, (size_t)n * 128);
    wpack_kernel<<<24, 256, 0, stream>>>(gcn_w, wfrag);

    const int ntiles = n / 16;  // 3125 (n divisible by 16)
    for (int l = 0; l < 3; ++l) {
        const ushort* hsrc = (l == 0) ? (const ushort*)xh : (const ushort*)(zh + (size_t)(l - 1) * 128);
        int ld = (l == 0) ? 128 : 384;
        gemm_mfma_kernel<<<ntiles, 256, 0, stream>>>(
            hsrc, ld, wfrag + (size_t)l * 2048 * 8, (ushort*)hw, ntiles);
        aggregate_kernel<<<(n * 64 + 255) / 256, 256, 0, stream>>>(
            hw, rowptr, csr_src, csr_coef, dinv, gcn_b + (size_t)l * 128, zh + (size_t)l * 128, n);
    }

    float inv_total = 1.0f / (2.0f * (float)p);
    loss_kernel<<<(2 * p + 15) / 16, 256, 0, stream>>>(
        (const ushort*)zh, pos, neg, pred_w, pred_b, out, p, inv_total);
}

// Round 5
// 361.537 us; speedup vs baseline: 5.7501x; 1.2513x over previous
//
#include <hip/hip_runtime.h>
#include <hip/hip_bf16.h>

#define DD 128

typedef __attribute__((ext_vector_type(8))) short short8;
typedef __attribute__((ext_vector_type(4))) float f32x4;

static __device__ __forceinline__ int gtid() {
    return blockIdx.x * blockDim.x + threadIdx.x;
}

static __device__ __forceinline__ ushort f2bfu(float f) {
    __hip_bfloat16 h = __float2bfloat16(f);
    return *reinterpret_cast<ushort*>(&h);
}

// ---- fp8 e4m3fn encode/decode (manual, RNE, subnormal-correct) ----
static __device__ __forceinline__ unsigned int fp8e(float f) {
    unsigned int s = (__float_as_uint(f) >> 31) << 7;
    float a = fabsf(f);
    if (a < 0.015625f) return s | (unsigned int)rintf(a * 512.0f);  // subnormal (incl. ->t=8)
    unsigned int u = __float_as_uint(a);
    u += 0x0007FFFFu + ((u >> 20) & 1u);           // RNE round mantissa to 3 bits
    unsigned int e8 = (u >> 23) - 120u;
    unsigned int m = (u >> 20) & 7u;
    if (e8 > 15u || (e8 == 15u && m == 7u)) return s | 0x7Eu;  // clamp to 448
    return s | (e8 << 3) | m;
}

static __device__ __forceinline__ float fp8d(unsigned int b) {
    unsigned int t = b & 0x7Fu;
    float v = (t >= 8u) ? __uint_as_float((t << 20) + 0x3C000000u)
                        : (float)t * 0.001953125f;  // 2^-9
    return (b & 0x80u) ? -v : v;
}

// ---------- degree / CSR build ----------

__global__ void count_kernel(int* __restrict__ counts, const int* __restrict__ dst, int e) {
    int i = gtid();
    if (i < e) atomicAdd(&counts[dst[i]], 1);
}

__global__ void dinv_kernel(float* __restrict__ dinv, const int* __restrict__ counts, int n) {
    int i = gtid();
    if (i < n) dinv[i] = rsqrtf(1.0f + (float)counts[i]);
}

__global__ __launch_bounds__(256) void scan_blocks(const int* __restrict__ counts,
                                                   int* __restrict__ rowptr,
                                                   int* __restrict__ partial, int n) {
    __shared__ int s[256];
    int i = blockIdx.x * 256 + threadIdx.x;
    int v = (i < n) ? counts[i] : 0;
    s[threadIdx.x] = v;
    __syncthreads();
    for (int off = 1; off < 256; off <<= 1) {
        int t = (threadIdx.x >= off) ? s[threadIdx.x - off] : 0;
        __syncthreads();
        s[threadIdx.x] += t;
        __syncthreads();
    }
    if (i < n) rowptr[i] = s[threadIdx.x] - v;
    if (threadIdx.x == 255) partial[blockIdx.x] = s[255];
}

__global__ __launch_bounds__(256) void scan_partials(int* __restrict__ partial,
                                                     int* __restrict__ partial2, int nb) {
    __shared__ int s[256];
    int v = (threadIdx.x < nb) ? partial[threadIdx.x] : 0;
    s[threadIdx.x] = v;
    __syncthreads();
    for (int off = 1; off < 256; off <<= 1) {
        int t = (threadIdx.x >= off) ? s[threadIdx.x - off] : 0;
        __syncthreads();
        s[threadIdx.x] += t;
        __syncthreads();
    }
    partial2[threadIdx.x] = s[threadIdx.x] - v;
}

__global__ __launch_bounds__(256) void add_offsets(int* __restrict__ rowptr,
                                                   int* __restrict__ cursor,
                                                   const int* __restrict__ partial2,
                                                   int n, int e) {
    int i = blockIdx.x * 256 + threadIdx.x;
    if (i < n) {
        int r = rowptr[i] + partial2[blockIdx.x];
        rowptr[i] = r;
        cursor[i] = r;
        if (i == n - 1) rowptr[n] = e;
    }
}

__global__ void fill_kernel(const int* __restrict__ ei, const float* __restrict__ dinv,
                            int* __restrict__ cursor, int* __restrict__ csr_src,
                            float* __restrict__ csr_coef, int e) {
    int i = gtid();
    if (i >= e) return;
    int s = ei[i];
    int d = ei[e + i];
    float c = dinv[s] * dinv[d];
    int pos = atomicAdd(&cursor[d], 1);
    csr_src[pos] = s;
    csr_coef[pos] = c;
}

// ---------- x -> bf16 ----------
__global__ void cvt_kernel(const float* __restrict__ x, __hip_bfloat16* __restrict__ xh, size_t m) {
    size_t i = (size_t)blockIdx.x * blockDim.x + threadIdx.x;
    if (i < m) xh[i] = __float2bfloat16(x[i]);
}

// ---------- W -> bf16 MFMA B-fragment order ----------
__global__ __launch_bounds__(256) void wpack_kernel(const float* __restrict__ gcn_w,
                                                    ushort* __restrict__ wfrag) {
    int tid = blockIdx.x * 256 + threadIdx.x;
    if (tid >= 3 * 4 * 8 * 64) return;
    int lane = tid & 63;
    int c = (tid >> 6) & 7;
    int s = (tid >> 9) & 3;
    int l = tid >> 11;
    const float* W = gcn_w + (size_t)l * 128 * 128;
    int col = c * 16 + (lane & 15);
    int k0 = s * 32 + (lane >> 4) * 8;
    ushort u[8];
#pragma unroll
    for (int j = 0; j < 8; ++j) {
        u[j] = f2bfu(W[(size_t)(k0 + j) * 128 + col]);
    }
    *reinterpret_cast<uint4*>(wfrag + (size_t)tid * 8) = *reinterpret_cast<const uint4*>(u);
}

// ---------- MFMA GEMM ----------
__global__ __launch_bounds__(256) void gemm_mfma_kernel(
    const ushort* __restrict__ hsrc, int ld, const ushort* __restrict__ wfrag,
    ushort* __restrict__ out, int ntiles) {
    int lane = threadIdx.x & 63;
    int wv = threadIdx.x >> 6;
    short8 b0[4], b1[4];
    int c0 = wv * 2;
#pragma unroll
    for (int s = 0; s < 4; ++s) {
        b0[s] = *reinterpret_cast<const short8*>(wfrag + ((size_t)(s * 8 + c0) * 64 + lane) * 8);
        b1[s] = *reinterpret_cast<const short8*>(wfrag + ((size_t)(s * 8 + c0 + 1) * 64 + lane) * 8);
    }
    int rlo = lane & 15;
    int kg = lane >> 4;
    for (int rt = blockIdx.x; rt < ntiles; rt += gridDim.x) {
        const ushort* ap = hsrc + (size_t)(rt * 16 + rlo) * ld + kg * 8;
        short8 a0 = *reinterpret_cast<const short8*>(ap);
        short8 a1 = *reinterpret_cast<const short8*>(ap + 32);
        short8 a2 = *reinterpret_cast<const short8*>(ap + 64);
        short8 a3 = *reinterpret_cast<const short8*>(ap + 96);
        f32x4 acc0 = {0.f, 0.f, 0.f, 0.f};
        f32x4 acc1 = {0.f, 0.f, 0.f, 0.f};
        acc0 = __builtin_amdgcn_mfma_f32_16x16x32_bf16(a0, b0[0], acc0, 0, 0, 0);
        acc1 = __builtin_amdgcn_mfma_f32_16x16x32_bf16(a0, b1[0], acc1, 0, 0, 0);
        acc0 = __builtin_amdgcn_mfma_f32_16x16x32_bf16(a1, b0[1], acc0, 0, 0, 0);
        acc1 = __builtin_amdgcn_mfma_f32_16x16x32_bf16(a1, b1[1], acc1, 0, 0, 0);
        acc0 = __builtin_amdgcn_mfma_f32_16x16x32_bf16(a2, b0[2], acc0, 0, 0, 0);
        acc1 = __builtin_amdgcn_mfma_f32_16x16x32_bf16(a2, b1[2], acc1, 0, 0, 0);
        acc0 = __builtin_amdgcn_mfma_f32_16x16x32_bf16(a3, b0[3], acc0, 0, 0, 0);
        acc1 = __builtin_amdgcn_mfma_f32_16x16x32_bf16(a3, b1[3], acc1, 0, 0, 0);
        int row0 = rt * 16 + kg * 4;
        ushort* orow = out + (size_t)row0 * 128 + wv * 32 + rlo;
#pragma unroll
        for (int r = 0; r < 4; ++r) {
            orow[(size_t)r * 128] = f2bfu(acc0[r]);
            orow[(size_t)r * 128 + 16] = f2bfu(acc1[r]);
        }
    }
}

// ---------- fused aggregate + self-loop + bias + relu, bf16 + fp8 outputs ----------
// one wave per dst row; 4 edges in flight (16-lane groups), uint4 gathers.
__global__ __launch_bounds__(256) void aggregate_kernel(
    const ushort* __restrict__ hw, const int* __restrict__ rowptr,
    const int* __restrict__ csr_src, const float* __restrict__ csr_coef,
    const float* __restrict__ dinv, const float* __restrict__ bias,
    ushort* __restrict__ zsl, unsigned char* __restrict__ zqsl, int n) {
    int gid = gtid();
    int row = gid >> 6;
    if (row >= n) return;
    int lane = threadIdx.x & 63;
    int g = lane >> 4;   // edge sub-group 0..3
    int c = lane & 15;   // feature chunk (8 feats each)
    int j0 = rowptr[row], j1 = rowptr[row + 1];
    float acc[8] = {0.f, 0.f, 0.f, 0.f, 0.f, 0.f, 0.f, 0.f};
    for (int j = j0 + g; j < j1; j += 4) {
        int s = csr_src[j];       // broadcast within 16-lane group
        float cf = csr_coef[j];
        uint4 v = *reinterpret_cast<const uint4*>(hw + (size_t)s * 128 + c * 8);
        const unsigned int* u = (const unsigned int*)&v;
#pragma unroll
        for (int q = 0; q < 4; ++q) {
            float f0 = __uint_as_float(u[q] << 16);
            float f1 = __uint_as_float(u[q] & 0xffff0000u);
            acc[2 * q] = fmaf(cf, f0, acc[2 * q]);
            acc[2 * q + 1] = fmaf(cf, f1, acc[2 * q + 1]);
        }
    }
    // cross-group reduce (groups hold partial sums of same feature chunk)
#pragma unroll
    for (int k = 0; k < 8; ++k) {
        acc[k] += __shfl_xor(acc[k], 16);
        acc[k] += __shfl_xor(acc[k], 32);
    }
    // self-loop + bias + relu
    float di = dinv[row];
    float d2 = di * di;
    uint4 sv = *reinterpret_cast<const uint4*>(hw + (size_t)row * 128 + c * 8);
    const unsigned int* su = (const unsigned int*)&sv;
#pragma unroll
    for (int q = 0; q < 4; ++q) {
        float f0 = __uint_as_float(su[q] << 16);
        float f1 = __uint_as_float(su[q] & 0xffff0000u);
        acc[2 * q] = fmaf(d2, f0, acc[2 * q]) + bias[c * 8 + 2 * q];
        acc[2 * q + 1] = fmaf(d2, f1, acc[2 * q + 1]) + bias[c * 8 + 2 * q + 1];
    }
#pragma unroll
    for (int k = 0; k < 8; ++k) acc[k] = fmaxf(acc[k], 0.f);
    if (lane < 16) {
        // bf16 store (8 elems = uint4)
        unsigned int pk[4];
#pragma unroll
        for (int q = 0; q < 4; ++q) {
            pk[q] = (unsigned int)f2bfu(acc[2 * q]) | ((unsigned int)f2bfu(acc[2 * q + 1]) << 16);
        }
        *reinterpret_cast<uint4*>(zsl + (size_t)row * 384 + c * 8) =
            *reinterpret_cast<const uint4*>(pk);
        // fp8 store (8 bytes = uint2)
        unsigned int q0 = fp8e(acc[0]) | (fp8e(acc[1]) << 8) | (fp8e(acc[2]) << 16) | (fp8e(acc[3]) << 24);
        unsigned int q1 = fp8e(acc[4]) | (fp8e(acc[5]) << 8) | (fp8e(acc[6]) << 16) | (fp8e(acc[7]) << 24);
        uint2 qq = {q0, q1};
        *reinterpret_cast<uint2*>(zqsl + (size_t)row * 384 + c * 8) = qq;
    }
}

// ---------- loss: fp8 rows, 8 lanes per pair ----------
__global__ __launch_bounds__(256) void loss_kernel(
    const unsigned char* __restrict__ zq, const int* __restrict__ pos,
    const int* __restrict__ neg, const float* __restrict__ pw, const float* __restrict__ pb,
    float* __restrict__ out, int p, float inv_total) {
    __shared__ float pwl[8 * 49];  // stride 49 to spread banks
    __shared__ float red[4];
    for (int i = threadIdx.x; i < 384; i += 256) {
        pwl[(i / 48) * 49 + (i % 48)] = pw[i];
    }
    if (threadIdx.x < 4) red[threadIdx.x] = 0.f;
    __syncthreads();
    int sub = threadIdx.x & 7;
    int pairIdx = (blockIdx.x * 256 + threadIdx.x) >> 3;
    float term = 0.f;
    if (pairIdx < 2 * p) {
        bool isneg = (pairIdx >= p);
        const int* pr = isneg ? neg : pos;
        int idx = isneg ? (pairIdx - p) : pairIdx;
        int a = pr[idx];
        int b = pr[p + idx];
        const unsigned char* za = zq + (size_t)a * 384 + sub * 48;
        const unsigned char* zb = zq + (size_t)b * 384 + sub * 48;
        const float* pwp = &pwl[sub * 49];
        float acc = 0.f;
#pragma unroll
        for (int j = 0; j < 3; ++j) {
            uint4 va = *reinterpret_cast<const uint4*>(za + j * 16);
            uint4 vb = *reinterpret_cast<const uint4*>(zb + j * 16);
            const unsigned int* ua = (const unsigned int*)&va;
            const unsigned int* ub = (const unsigned int*)&vb;
#pragma unroll
            for (int q = 0; q < 4; ++q) {
#pragma unroll
                for (int by = 0; by < 4; ++by) {
                    float fa = fp8d((ua[q] >> (8 * by)) & 0xFFu);
                    float fb = fp8d((ub[q] >> (8 * by)) & 0xFFu);
                    acc = fmaf(fa * fb, pwp[j * 16 + q * 4 + by], acc);
                }
            }
        }
#pragma unroll
        for (int off = 1; off < 8; off <<= 1) acc += __shfl_xor(acc, off);
        if (sub == 0) {
            float logit = acc + pb[0];
            if (isneg) logit = -logit;
            float t = -logit;
            term = (fmaxf(t, 0.f) + log1pf(expf(-fabsf(t)))) * inv_total;
        } else {
            term = 0.f;
        }
    }
    // wave reduce the 8 leader lanes, then block reduce
#pragma unroll
    for (int off = 8; off < 64; off <<= 1) term += __shfl_xor(term, off);
    if ((threadIdx.x & 63) == 0) red[threadIdx.x >> 6] = term;
    __syncthreads();
    if (threadIdx.x == 0) atomicAdd(out, red[0] + red[1] + red[2] + red[3]);
}

extern "C" void kernel_launch(void* const* d_in, const int* in_sizes, int n_in,
                              void* d_out, int out_size, void* d_ws, size_t ws_size,
                              hipStream_t stream) {
    const float* x      = (const float*)d_in[0];
    const int*   ei     = (const int*)d_in[1];
    const int*   pos    = (const int*)d_in[2];
    const int*   neg    = (const int*)d_in[3];
    const float* gcn_w  = (const float*)d_in[4];
    const float* gcn_b  = (const float*)d_in[5];
    const float* pred_w = (const float*)d_in[6];
    const float* pred_b = (const float*)d_in[7];
    float* out = (float*)d_out;

    const int n = in_sizes[0] / DD;     // 50000
    const int e = in_sizes[1] / 2;      // 640000
    const int p = in_sizes[2] / 2;      // 100000
    const int nb = (n + 255) / 256;

    char* ws = (char*)d_ws;
    size_t off = 0;
    auto alloc = [&](size_t bytes) {
        void* ptr = ws + off;
        off += (bytes + 255) & ~(size_t)255;
        return ptr;
    };
    float* dinv      = (float*)alloc((size_t)n * 4);
    int*   counts    = (int*)alloc((size_t)n * 4);
    int*   rowptr    = (int*)alloc((size_t)(n + 1) * 4);
    int*   cursor    = (int*)alloc((size_t)n * 4);
    int*   partial   = (int*)alloc(256 * 4);
    int*   partial2  = (int*)alloc(256 * 4);
    int*   csr_src   = (int*)alloc((size_t)e * 4);
    float* csr_coef  = (float*)alloc((size_t)e * 4);
    ushort* wfrag    = (ushort*)alloc((size_t)3 * 2048 * 8 * 2);
    ushort* xh = (ushort*)alloc((size_t)n * 128 * 2);
    ushort* hw = (ushort*)alloc((size_t)n * 128 * 2);
    ushort* zh = (ushort*)alloc((size_t)n * 384 * 2);
    unsigned char* zq = (unsigned char*)alloc((size_t)n * 384);
    (void)ws_size;

    hipMemsetAsync(counts, 0, (size_t)n * 4, stream);
    hipMemsetAsync(d_out, 0, (size_t)out_size * 4, stream);

    count_kernel<<<(e + 255) / 256, 256, 0, stream>>>(counts, ei + e, e);
    dinv_kernel<<<nb, 256, 0, stream>>>(dinv, counts, n);
    scan_blocks<<<nb, 256, 0, stream>>>(counts, rowptr, partial, n);
    scan_partials<<<1, 256, 0, stream>>>(partial, partial2, nb);
    add_offsets<<<nb, 256, 0, stream>>>(rowptr, cursor, partial2, n, e);
    fill_kernel<<<(e + 255) / 256, 256, 0, stream>>>(ei, dinv, cursor, csr_src, csr_coef, e);

    cvt_kernel<<<(int)(((size_t)n * 128 + 255) / 256), 256, 0, stream>>>(
        x, (__hip_bfloat16*)xh, (size_t)n * 128);
    wpack_kernel<<<24, 256, 0, stream>>>(gcn_w, wfrag);

    const int ntiles = n / 16;
    for (int l = 0; l < 3; ++l) {
        const ushort* hsrc = (l == 0) ? xh : (zh + (size_t)(l - 1) * 128);
        int ld = (l == 0) ? 128 : 384;
        gemm_mfma_kernel<<<ntiles, 256, 0, stream>>>(
            hsrc, ld, wfrag + (size_t)l * 2048 * 8, hw, ntiles);
        aggregate_kernel<<<(n * 64 + 255) / 256, 256, 0, stream>>>(
            hw, rowptr, csr_src, csr_coef, dinv, gcn_b + (size_t)l * 128,
            zh + (size_t)l * 128, zq + (size_t)l * 128, n);
    }

    float inv_total = 1.0f / (2.0f * (float)p);
    loss_kernel<<<(2 * p * 8 + 255) / 256, 256, 0, stream>>>(
        zq, pos, neg, pred_w, pred_b, out, p, inv_total);
}

// Round 6
// 340.324 us; speedup vs baseline: 6.1086x; 1.0623x over previous
//
#include <hip/hip_runtime.h>
#include <hip/hip_bf16.h>

#define DD 128

typedef __attribute__((ext_vector_type(8))) short short8;
typedef __attribute__((ext_vector_type(4))) float f32x4;

static __device__ __forceinline__ int gtid() {
    return blockIdx.x * blockDim.x + threadIdx.x;
}

static __device__ __forceinline__ ushort f2bfu(float f) {
    __hip_bfloat16 h = __float2bfloat16(f);
    return *reinterpret_cast<ushort*>(&h);
}

// ---- fp8 e4m3fn encode (manual, RNE, subnormal-correct) ----
static __device__ __forceinline__ unsigned int fp8e(float f) {
    unsigned int s = (__float_as_uint(f) >> 31) << 7;
    float a = fabsf(f);
    if (a < 0.015625f) return s | (unsigned int)rintf(a * 512.0f);  // subnormal
    unsigned int u = __float_as_uint(a);
    u += 0x0007FFFFu + ((u >> 20) & 1u);           // RNE round mantissa to 3 bits
    unsigned int e8 = (u >> 23) - 120u;
    unsigned int m = (u >> 20) & 7u;
    if (e8 > 15u || (e8 == 15u && m == 7u)) return s | 0x7Eu;  // clamp to 448
    return s | (e8 << 3) | m;
}

// ---------- degree / CSR build ----------

__global__ void count_kernel(int* __restrict__ counts, const int* __restrict__ dst, int e) {
    int i = gtid();
    if (i < e) atomicAdd(&counts[dst[i]], 1);
}

__global__ void dinv_kernel(float* __restrict__ dinv, const int* __restrict__ counts, int n) {
    int i = gtid();
    if (i < n) dinv[i] = rsqrtf(1.0f + (float)counts[i]);
}

__global__ __launch_bounds__(256) void scan_blocks(const int* __restrict__ counts,
                                                   int* __restrict__ rowptr,
                                                   int* __restrict__ partial, int n) {
    __shared__ int s[256];
    int i = blockIdx.x * 256 + threadIdx.x;
    int v = (i < n) ? counts[i] : 0;
    s[threadIdx.x] = v;
    __syncthreads();
    for (int off = 1; off < 256; off <<= 1) {
        int t = (threadIdx.x >= off) ? s[threadIdx.x - off] : 0;
        __syncthreads();
        s[threadIdx.x] += t;
        __syncthreads();
    }
    if (i < n) rowptr[i] = s[threadIdx.x] - v;
    if (threadIdx.x == 255) partial[blockIdx.x] = s[255];
}

__global__ __launch_bounds__(256) void scan_partials(int* __restrict__ partial,
                                                     int* __restrict__ partial2, int nb) {
    __shared__ int s[256];
    int v = (threadIdx.x < nb) ? partial[threadIdx.x] : 0;
    s[threadIdx.x] = v;
    __syncthreads();
    for (int off = 1; off < 256; off <<= 1) {
        int t = (threadIdx.x >= off) ? s[threadIdx.x - off] : 0;
        __syncthreads();
        s[threadIdx.x] += t;
        __syncthreads();
    }
    partial2[threadIdx.x] = s[threadIdx.x] - v;
}

__global__ __launch_bounds__(256) void add_offsets(int* __restrict__ rowptr,
                                                   int* __restrict__ cursor,
                                                   const int* __restrict__ partial2,
                                                   int n, int e) {
    int i = blockIdx.x * 256 + threadIdx.x;
    if (i < n) {
        int r = rowptr[i] + partial2[blockIdx.x];
        rowptr[i] = r;
        cursor[i] = r;
        if (i == n - 1) rowptr[n] = e;
    }
}

__global__ void fill_kernel(const int* __restrict__ ei, const float* __restrict__ dinv,
                            int* __restrict__ cursor, int* __restrict__ csr_src,
                            float* __restrict__ csr_coef, int e) {
    int i = gtid();
    if (i >= e) return;
    int s = ei[i];
    int d = ei[e + i];
    float c = dinv[s] * dinv[d];
    int pos = atomicAdd(&cursor[d], 1);
    csr_src[pos] = s;
    csr_coef[pos] = c;
}

// ---------- x -> bf16 ----------
__global__ void cvt_kernel(const float* __restrict__ x, __hip_bfloat16* __restrict__ xh, size_t m) {
    size_t i = (size_t)blockIdx.x * blockDim.x + threadIdx.x;
    if (i < m) xh[i] = __float2bfloat16(x[i]);
}

// ---------- W -> bf16 MFMA B-fragment order ----------
__global__ __launch_bounds__(256) void wpack_kernel(const float* __restrict__ gcn_w,
                                                    ushort* __restrict__ wfrag) {
    int tid = blockIdx.x * 256 + threadIdx.x;
    if (tid >= 3 * 4 * 8 * 64) return;
    int lane = tid & 63;
    int c = (tid >> 6) & 7;
    int s = (tid >> 9) & 3;
    int l = tid >> 11;
    const float* W = gcn_w + (size_t)l * 128 * 128;
    int col = c * 16 + (lane & 15);
    int k0 = s * 32 + (lane >> 4) * 8;
    ushort u[8];
#pragma unroll
    for (int j = 0; j < 8; ++j) {
        u[j] = f2bfu(W[(size_t)(k0 + j) * 128 + col]);
    }
    *reinterpret_cast<uint4*>(wfrag + (size_t)tid * 8) = *reinterpret_cast<const uint4*>(u);
}

// ---------- MFMA GEMM ----------
__global__ __launch_bounds__(256) void gemm_mfma_kernel(
    const ushort* __restrict__ hsrc, int ld, const ushort* __restrict__ wfrag,
    ushort* __restrict__ out, int ntiles) {
    int lane = threadIdx.x & 63;
    int wv = threadIdx.x >> 6;
    short8 b0[4], b1[4];
    int c0 = wv * 2;
#pragma unroll
    for (int s = 0; s < 4; ++s) {
        b0[s] = *reinterpret_cast<const short8*>(wfrag + ((size_t)(s * 8 + c0) * 64 + lane) * 8);
        b1[s] = *reinterpret_cast<const short8*>(wfrag + ((size_t)(s * 8 + c0 + 1) * 64 + lane) * 8);
    }
    int rlo = lane & 15;
    int kg = lane >> 4;
    for (int rt = blockIdx.x; rt < ntiles; rt += gridDim.x) {
        const ushort* ap = hsrc + (size_t)(rt * 16 + rlo) * ld + kg * 8;
        short8 a0 = *reinterpret_cast<const short8*>(ap);
        short8 a1 = *reinterpret_cast<const short8*>(ap + 32);
        short8 a2 = *reinterpret_cast<const short8*>(ap + 64);
        short8 a3 = *reinterpret_cast<const short8*>(ap + 96);
        f32x4 acc0 = {0.f, 0.f, 0.f, 0.f};
        f32x4 acc1 = {0.f, 0.f, 0.f, 0.f};
        acc0 = __builtin_amdgcn_mfma_f32_16x16x32_bf16(a0, b0[0], acc0, 0, 0, 0);
        acc1 = __builtin_amdgcn_mfma_f32_16x16x32_bf16(a0, b1[0], acc1, 0, 0, 0);
        acc0 = __builtin_amdgcn_mfma_f32_16x16x32_bf16(a1, b0[1], acc0, 0, 0, 0);
        acc1 = __builtin_amdgcn_mfma_f32_16x16x32_bf16(a1, b1[1], acc1, 0, 0, 0);
        acc0 = __builtin_amdgcn_mfma_f32_16x16x32_bf16(a2, b0[2], acc0, 0, 0, 0);
        acc1 = __builtin_amdgcn_mfma_f32_16x16x32_bf16(a2, b1[2], acc1, 0, 0, 0);
        acc0 = __builtin_amdgcn_mfma_f32_16x16x32_bf16(a3, b0[3], acc0, 0, 0, 0);
        acc1 = __builtin_amdgcn_mfma_f32_16x16x32_bf16(a3, b1[3], acc1, 0, 0, 0);
        int row0 = rt * 16 + kg * 4;
        ushort* orow = out + (size_t)row0 * 128 + wv * 32 + rlo;
#pragma unroll
        for (int r = 0; r < 4; ++r) {
            orow[(size_t)r * 128] = f2bfu(acc0[r]);
            orow[(size_t)r * 128 + 16] = f2bfu(acc1[r]);
        }
    }
}

// ---------- fused aggregate + self-loop + bias + relu; bf16 + fp8 + fp8(pw-scaled) outputs ----------
__global__ __launch_bounds__(256) void aggregate_kernel(
    const ushort* __restrict__ hw, const int* __restrict__ rowptr,
    const int* __restrict__ csr_src, const float* __restrict__ csr_coef,
    const float* __restrict__ dinv, const float* __restrict__ bias,
    const float* __restrict__ pwsl,
    ushort* __restrict__ zsl, unsigned char* __restrict__ zqsl,
    unsigned char* __restrict__ zqwsl, int n) {
    int gid = gtid();
    int row = gid >> 6;
    if (row >= n) return;
    int lane = threadIdx.x & 63;
    int g = lane >> 4;   // edge sub-group 0..3
    int c = lane & 15;   // feature chunk (8 feats each)
    int j0 = rowptr[row], j1 = rowptr[row + 1];
    float acc[8] = {0.f, 0.f, 0.f, 0.f, 0.f, 0.f, 0.f, 0.f};
    for (int j = j0 + g; j < j1; j += 4) {
        int s = csr_src[j];
        float cf = csr_coef[j];
        uint4 v = *reinterpret_cast<const uint4*>(hw + (size_t)s * 128 + c * 8);
        const unsigned int* u = (const unsigned int*)&v;
#pragma unroll
        for (int q = 0; q < 4; ++q) {
            float f0 = __uint_as_float(u[q] << 16);
            float f1 = __uint_as_float(u[q] & 0xffff0000u);
            acc[2 * q] = fmaf(cf, f0, acc[2 * q]);
            acc[2 * q + 1] = fmaf(cf, f1, acc[2 * q + 1]);
        }
    }
#pragma unroll
    for (int k = 0; k < 8; ++k) {
        acc[k] += __shfl_xor(acc[k], 16);
        acc[k] += __shfl_xor(acc[k], 32);
    }
    float di = dinv[row];
    float d2 = di * di;
    uint4 sv = *reinterpret_cast<const uint4*>(hw + (size_t)row * 128 + c * 8);
    const unsigned int* su = (const unsigned int*)&sv;
#pragma unroll
    for (int q = 0; q < 4; ++q) {
        float f0 = __uint_as_float(su[q] << 16);
        float f1 = __uint_as_float(su[q] & 0xffff0000u);
        acc[2 * q] = fmaf(d2, f0, acc[2 * q]) + bias[c * 8 + 2 * q];
        acc[2 * q + 1] = fmaf(d2, f1, acc[2 * q + 1]) + bias[c * 8 + 2 * q + 1];
    }
#pragma unroll
    for (int k = 0; k < 8; ++k) acc[k] = fmaxf(acc[k], 0.f);
    if (lane < 16) {
        // bf16 store
        unsigned int pk[4];
#pragma unroll
        for (int q = 0; q < 4; ++q) {
            pk[q] = (unsigned int)f2bfu(acc[2 * q]) | ((unsigned int)f2bfu(acc[2 * q + 1]) << 16);
        }
        *reinterpret_cast<uint4*>(zsl + (size_t)row * 384 + c * 8) =
            *reinterpret_cast<const uint4*>(pk);
        // fp8 plain store
        unsigned int q0 = fp8e(acc[0]) | (fp8e(acc[1]) << 8) | (fp8e(acc[2]) << 16) | (fp8e(acc[3]) << 24);
        unsigned int q1 = fp8e(acc[4]) | (fp8e(acc[5]) << 8) | (fp8e(acc[6]) << 16) | (fp8e(acc[7]) << 24);
        uint2 qq = {q0, q1};
        *reinterpret_cast<uint2*>(zqsl + (size_t)row * 384 + c * 8) = qq;
        // fp8 pw-scaled store (×8 to stay out of subnormal range; loss divides by 8)
        float w[8];
#pragma unroll
        for (int k = 0; k < 8; ++k) w[k] = acc[k] * pwsl[c * 8 + k] * 8.0f;
        unsigned int w0 = fp8e(w[0]) | (fp8e(w[1]) << 8) | (fp8e(w[2]) << 16) | (fp8e(w[3]) << 24);
        unsigned int w1 = fp8e(w[4]) | (fp8e(w[5]) << 8) | (fp8e(w[6]) << 16) | (fp8e(w[7]) << 24);
        uint2 ww = {w0, w1};
        *reinterpret_cast<uint2*>(zqwsl + (size_t)row * 384 + c * 8) = ww;
    }
}

// ---------- loss: fp8 MFMA diagonal dot; 16 pairs per wave ----------
// logit[i] = (1/8) * sum_d zq[a_i][d] * zqw[b_i][d]   (zqw pre-scaled by 8*pw)
__global__ __launch_bounds__(256) void loss_mfma_kernel(
    const unsigned char* __restrict__ zq, const unsigned char* __restrict__ zqw,
    const int* __restrict__ pos, const int* __restrict__ neg,
    const float* __restrict__ pb, float* __restrict__ out, int p, float inv_total) {
    __shared__ float red[4];
    int lane = threadIdx.x & 63;
    int wv = threadIdx.x >> 6;
    int pairBase = (blockIdx.x * 4 + wv) * 16;
    float term = 0.f;
    if (pairBase < 2 * p) {
        int m = lane & 15;   // A-row / B-col = pair within wave
        int kg = lane >> 4;  // k-octet
        int pi = pairBase + m;
        int pic = (pi < 2 * p) ? pi : (2 * p - 1);
        bool isneg = (pic >= p);
        const int* pr = isneg ? neg : pos;
        int idx = isneg ? (pic - p) : pic;
        int a = pr[idx];
        int b = pr[p + idx];
        const long* pa = reinterpret_cast<const long*>(zq + (size_t)a * 384) + kg;
        const long* pbw = reinterpret_cast<const long*>(zqw + (size_t)b * 384) + kg;
        f32x4 acc = {0.f, 0.f, 0.f, 0.f};
#pragma unroll
        for (int s = 0; s < 12; ++s) {
            long av = pa[s * 4];
            long bv = pbw[s * 4];
            acc = __builtin_amdgcn_mfma_f32_16x16x32_fp8_fp8(av, bv, acc, 0, 0, 0);
        }
        // diagonal: lane = 16*(i>>2)+i holds D[i][i] in reg (i&3)
        bool isdiag = (lane >> 4) == ((lane & 15) >> 2);
        int r2 = lane & 3;
        float v = (r2 == 0) ? acc[0] : (r2 == 1) ? acc[1] : (r2 == 2) ? acc[2] : acc[3];
        if (isdiag && pi < 2 * p) {
            float logit = v * 0.125f + pb[0];
            float t = isneg ? logit : -logit;  // softplus argument
            term = (fmaxf(t, 0.f) + log1pf(expf(-fabsf(t)))) * inv_total;
        }
    }
#pragma unroll
    for (int off = 1; off < 64; off <<= 1) term += __shfl_xor(term, off);
    if (lane == 0) red[wv] = term;
    __syncthreads();
    if (threadIdx.x == 0) atomicAdd(out, red[0] + red[1] + red[2] + red[3]);
}

extern "C" void kernel_launch(void* const* d_in, const int* in_sizes, int n_in,
                              void* d_out, int out_size, void* d_ws, size_t ws_size,
                              hipStream_t stream) {
    const float* x      = (const float*)d_in[0];
    const int*   ei     = (const int*)d_in[1];
    const int*   pos    = (const int*)d_in[2];
    const int*   neg    = (const int*)d_in[3];
    const float* gcn_w  = (const float*)d_in[4];
    const float* gcn_b  = (const float*)d_in[5];
    const float* pred_w = (const float*)d_in[6];
    const float* pred_b = (const float*)d_in[7];
    float* out = (float*)d_out;

    const int n = in_sizes[0] / DD;     // 50000
    const int e = in_sizes[1] / 2;      // 640000
    const int p = in_sizes[2] / 2;      // 100000
    const int nb = (n + 255) / 256;

    char* ws = (char*)d_ws;
    size_t off = 0;
    auto alloc = [&](size_t bytes) {
        void* ptr = ws + off;
        off += (bytes + 255) & ~(size_t)255;
        return ptr;
    };
    float* dinv      = (float*)alloc((size_t)n * 4);
    int*   counts    = (int*)alloc((size_t)n * 4);
    int*   rowptr    = (int*)alloc((size_t)(n + 1) * 4);
    int*   cursor    = (int*)alloc((size_t)n * 4);
    int*   partial   = (int*)alloc(256 * 4);
    int*   partial2  = (int*)alloc(256 * 4);
    int*   csr_src   = (int*)alloc((size_t)e * 4);
    float* csr_coef  = (float*)alloc((size_t)e * 4);
    ushort* wfrag    = (ushort*)alloc((size_t)3 * 2048 * 8 * 2);
    ushort* xh = (ushort*)alloc((size_t)n * 128 * 2);
    ushort* hw = (ushort*)alloc((size_t)n * 128 * 2);
    ushort* zh = (ushort*)alloc((size_t)n * 384 * 2);
    unsigned char* zq  = (unsigned char*)alloc((size_t)n * 384);
    unsigned char* zqw = (unsigned char*)alloc((size_t)n * 384);
    (void)ws_size;

    hipMemsetAsync(counts, 0, (size_t)n * 4, stream);
    hipMemsetAsync(d_out, 0, (size_t)out_size * 4, stream);

    count_kernel<<<(e + 255) / 256, 256, 0, stream>>>(counts, ei + e, e);
    dinv_kernel<<<nb, 256, 0, stream>>>(dinv, counts, n);
    scan_blocks<<<nb, 256, 0, stream>>>(counts, rowptr, partial, n);
    scan_partials<<<1, 256, 0, stream>>>(partial, partial2, nb);
    add_offsets<<<nb, 256, 0, stream>>>(rowptr, cursor, partial2, n, e);
    fill_kernel<<<(e + 255) / 256, 256, 0, stream>>>(ei, dinv, cursor, csr_src, csr_coef, e);

    cvt_kernel<<<(int)(((size_t)n * 128 + 255) / 256), 256, 0, stream>>>(
        x, (__hip_bfloat16*)xh, (size_t)n * 128);
    wpack_kernel<<<24, 256, 0, stream>>>(gcn_w, wfrag);

    const int ntiles = n / 16;
    for (int l = 0; l < 3; ++l) {
        const ushort* hsrc = (l == 0) ? xh : (zh + (size_t)(l - 1) * 128);
        int ld = (l == 0) ? 128 : 384;
        gemm_mfma_kernel<<<ntiles, 256, 0, stream>>>(
            hsrc, ld, wfrag + (size_t)l * 2048 * 8, hw, ntiles);
        aggregate_kernel<<<(n * 64 + 255) / 256, 256, 0, stream>>>(
            hw, rowptr, csr_src, csr_coef, dinv, gcn_b + (size_t)l * 128,
            pred_w + (size_t)l * 128,
            zh + (size_t)l * 128, zq + (size_t)l * 128, zqw + (size_t)l * 128, n);
    }

    float inv_total = 1.0f / (2.0f * (float)p);
    int lossWaves = (2 * p + 15) / 16;
    int lossBlocks = (lossWaves + 3) / 4;
    loss_mfma_kernel<<<lossBlocks, 256, 0, stream>>>(
        zq, zqw, pos, neg, pred_b, out, p, inv_total);
}

// Round 7
// 302.376 us; speedup vs baseline: 6.8752x; 1.1255x over previous
//
#include <hip/hip_runtime.h>
#include <hip/hip_bf16.h>

#define DD 128

typedef __attribute__((ext_vector_type(8))) short short8;
typedef __attribute__((ext_vector_type(4))) float f32x4;

static __device__ __forceinline__ int gtid() {
    return blockIdx.x * blockDim.x + threadIdx.x;
}

static __device__ __forceinline__ ushort f2bfu(float f) {
    __hip_bfloat16 h = __float2bfloat16(f);
    return *reinterpret_cast<ushort*>(&h);
}

// ---- fp8 e4m3fn encode (manual fallback, RNE, subnormal-correct) ----
static __device__ __forceinline__ unsigned int fp8e(float f) {
    unsigned int s = (__float_as_uint(f) >> 31) << 7;
    float a = fabsf(f);
    if (a < 0.015625f) return s | (unsigned int)rintf(a * 512.0f);  // subnormal
    unsigned int u = __float_as_uint(a);
    u += 0x0007FFFFu + ((u >> 20) & 1u);           // RNE round mantissa to 3 bits
    unsigned int e8 = (u >> 23) - 120u;
    unsigned int m = (u >> 20) & 7u;
    if (e8 > 15u || (e8 == 15u && m == 7u)) return s | 0x7Eu;  // clamp to 448
    return s | (e8 << 3) | m;
}

// pack 4 f32 -> 4 fp8 bytes (HW cvt when available)
static __device__ __forceinline__ unsigned int pk8x4(float a, float b, float c, float d) {
#if __has_builtin(__builtin_amdgcn_cvt_pk_fp8_f32)
    int v = __builtin_amdgcn_cvt_pk_fp8_f32(a, b, 0, false);
    v = __builtin_amdgcn_cvt_pk_fp8_f32(c, d, v, true);
    return (unsigned int)v;
#else
    return fp8e(a) | (fp8e(b) << 8) | (fp8e(c) << 16) | (fp8e(d) << 24);
#endif
}

// ---------- degree / CSR build ----------

__global__ void count_kernel(int* __restrict__ counts, const int* __restrict__ dst, int e) {
    int i = gtid();
    if (i < e) atomicAdd(&counts[dst[i]], 1);
}

__global__ void dinv_kernel(float* __restrict__ dinv, const int* __restrict__ counts, int n) {
    int i = gtid();
    if (i < n) dinv[i] = rsqrtf(1.0f + (float)counts[i]);
}

__global__ __launch_bounds__(256) void scan_blocks(const int* __restrict__ counts,
                                                   int* __restrict__ rowptr,
                                                   int* __restrict__ partial, int n) {
    __shared__ int s[256];
    int i = blockIdx.x * 256 + threadIdx.x;
    int v = (i < n) ? counts[i] : 0;
    s[threadIdx.x] = v;
    __syncthreads();
    for (int off = 1; off < 256; off <<= 1) {
        int t = (threadIdx.x >= off) ? s[threadIdx.x - off] : 0;
        __syncthreads();
        s[threadIdx.x] += t;
        __syncthreads();
    }
    if (i < n) rowptr[i] = s[threadIdx.x] - v;
    if (threadIdx.x == 255) partial[blockIdx.x] = s[255];
}

__global__ __launch_bounds__(256) void scan_partials(int* __restrict__ partial,
                                                     int* __restrict__ partial2, int nb) {
    __shared__ int s[256];
    int v = (threadIdx.x < nb) ? partial[threadIdx.x] : 0;
    s[threadIdx.x] = v;
    __syncthreads();
    for (int off = 1; off < 256; off <<= 1) {
        int t = (threadIdx.x >= off) ? s[threadIdx.x - off] : 0;
        __syncthreads();
        s[threadIdx.x] += t;
        __syncthreads();
    }
    partial2[threadIdx.x] = s[threadIdx.x] - v;
}

__global__ __launch_bounds__(256) void add_offsets(int* __restrict__ rowptr,
                                                   int* __restrict__ cursor,
                                                   const int* __restrict__ partial2,
                                                   int n, int e) {
    int i = blockIdx.x * 256 + threadIdx.x;
    if (i < n) {
        int r = rowptr[i] + partial2[blockIdx.x];
        rowptr[i] = r;
        cursor[i] = r;
        if (i == n - 1) rowptr[n] = e;
    }
}

__global__ void fill_kernel(const int* __restrict__ ei, const float* __restrict__ dinv,
                            int* __restrict__ cursor, int* __restrict__ csr_src,
                            float* __restrict__ csr_coef, int e) {
    int i = gtid();
    if (i >= e) return;
    int s = ei[i];
    int d = ei[e + i];
    float c = dinv[s] * dinv[d];
    int pos = atomicAdd(&cursor[d], 1);
    csr_src[pos] = s;
    csr_coef[pos] = c;
}

// ---------- x -> bf16 ----------
__global__ void cvt_kernel(const float* __restrict__ x, __hip_bfloat16* __restrict__ xh, size_t m) {
    size_t i = (size_t)blockIdx.x * blockDim.x + threadIdx.x;
    if (i < m) xh[i] = __float2bfloat16(x[i]);
}

// ---------- W -> bf16 MFMA B-fragment order ----------
__global__ __launch_bounds__(256) void wpack_kernel(const float* __restrict__ gcn_w,
                                                    ushort* __restrict__ wfrag) {
    int tid = blockIdx.x * 256 + threadIdx.x;
    if (tid >= 3 * 4 * 8 * 64) return;
    int lane = tid & 63;
    int c = (tid >> 6) & 7;
    int s = (tid >> 9) & 3;
    int l = tid >> 11;
    const float* W = gcn_w + (size_t)l * 128 * 128;
    int col = c * 16 + (lane & 15);
    int k0 = s * 32 + (lane >> 4) * 8;
    ushort u[8];
#pragma unroll
    for (int j = 0; j < 8; ++j) {
        u[j] = f2bfu(W[(size_t)(k0 + j) * 128 + col]);
    }
    *reinterpret_cast<uint4*>(wfrag + (size_t)tid * 8) = *reinterpret_cast<const uint4*>(u);
}

// ---------- MFMA GEMM ----------
__global__ __launch_bounds__(256) void gemm_mfma_kernel(
    const ushort* __restrict__ hsrc, int ld, const ushort* __restrict__ wfrag,
    ushort* __restrict__ out, int ntiles) {
    int lane = threadIdx.x & 63;
    int wv = threadIdx.x >> 6;
    short8 b0[4], b1[4];
    int c0 = wv * 2;
#pragma unroll
    for (int s = 0; s < 4; ++s) {
        b0[s] = *reinterpret_cast<const short8*>(wfrag + ((size_t)(s * 8 + c0) * 64 + lane) * 8);
        b1[s] = *reinterpret_cast<const short8*>(wfrag + ((size_t)(s * 8 + c0 + 1) * 64 + lane) * 8);
    }
    int rlo = lane & 15;
    int kg = lane >> 4;
    for (int rt = blockIdx.x; rt < ntiles; rt += gridDim.x) {
        const ushort* ap = hsrc + (size_t)(rt * 16 + rlo) * ld + kg * 8;
        short8 a0 = *reinterpret_cast<const short8*>(ap);
        short8 a1 = *reinterpret_cast<const short8*>(ap + 32);
        short8 a2 = *reinterpret_cast<const short8*>(ap + 64);
        short8 a3 = *reinterpret_cast<const short8*>(ap + 96);
        f32x4 acc0 = {0.f, 0.f, 0.f, 0.f};
        f32x4 acc1 = {0.f, 0.f, 0.f, 0.f};
        acc0 = __builtin_amdgcn_mfma_f32_16x16x32_bf16(a0, b0[0], acc0, 0, 0, 0);
        acc1 = __builtin_amdgcn_mfma_f32_16x16x32_bf16(a0, b1[0], acc1, 0, 0, 0);
        acc0 = __builtin_amdgcn_mfma_f32_16x16x32_bf16(a1, b0[1], acc0, 0, 0, 0);
        acc1 = __builtin_amdgcn_mfma_f32_16x16x32_bf16(a1, b1[1], acc1, 0, 0, 0);
        acc0 = __builtin_amdgcn_mfma_f32_16x16x32_bf16(a2, b0[2], acc0, 0, 0, 0);
        acc1 = __builtin_amdgcn_mfma_f32_16x16x32_bf16(a2, b1[2], acc1, 0, 0, 0);
        acc0 = __builtin_amdgcn_mfma_f32_16x16x32_bf16(a3, b0[3], acc0, 0, 0, 0);
        acc1 = __builtin_amdgcn_mfma_f32_16x16x32_bf16(a3, b1[3], acc1, 0, 0, 0);
        int row0 = rt * 16 + kg * 4;
        ushort* orow = out + (size_t)row0 * 128 + wv * 32 + rlo;
#pragma unroll
        for (int r = 0; r < 4; ++r) {
            orow[(size_t)r * 128] = f2bfu(acc0[r]);
            orow[(size_t)r * 128 + 16] = f2bfu(acc1[r]);
        }
    }
}

// ---------- fused aggregate + self-loop + bias + relu; bf16 + fp8 + fp8(pw-scaled) outputs ----------
// one wave per dst row; 4 edges in flight (16-lane groups), uint4 gathers.
// Epilogue distributed across sub-groups: g0 bf16, g1 zq, g2/g3 zqw halves.
__global__ __launch_bounds__(256) void aggregate_kernel(
    const ushort* __restrict__ hw, const int* __restrict__ rowptr,
    const int* __restrict__ csr_src, const float* __restrict__ csr_coef,
    const float* __restrict__ dinv, const float* __restrict__ bias,
    const float* __restrict__ pwsl,
    ushort* __restrict__ zsl, unsigned char* __restrict__ zqsl,
    unsigned char* __restrict__ zqwsl, int n) {
    int gid = gtid();
    int row = gid >> 6;
    if (row >= n) return;
    int lane = threadIdx.x & 63;
    int g = lane >> 4;   // edge sub-group 0..3
    int c = lane & 15;   // feature chunk (8 feats each)
    int j0 = rowptr[row], j1 = rowptr[row + 1];
    float acc[8] = {0.f, 0.f, 0.f, 0.f, 0.f, 0.f, 0.f, 0.f};
    for (int j = j0 + g; j < j1; j += 4) {
        int s = csr_src[j];
        float cf = csr_coef[j];
        uint4 v = *reinterpret_cast<const uint4*>(hw + (size_t)s * 128 + c * 8);
        const unsigned int* u = (const unsigned int*)&v;
#pragma unroll
        for (int q = 0; q < 4; ++q) {
            float f0 = __uint_as_float(u[q] << 16);
            float f1 = __uint_as_float(u[q] & 0xffff0000u);
            acc[2 * q] = fmaf(cf, f0, acc[2 * q]);
            acc[2 * q + 1] = fmaf(cf, f1, acc[2 * q + 1]);
        }
    }
#pragma unroll
    for (int k = 0; k < 8; ++k) {
        acc[k] += __shfl_xor(acc[k], 16);
        acc[k] += __shfl_xor(acc[k], 32);
    }
    // self-loop + bias + relu (all lanes; every group holds the full reduced chunk)
    float di = dinv[row];
    float d2 = di * di;
    uint4 sv = *reinterpret_cast<const uint4*>(hw + (size_t)row * 128 + c * 8);
    const unsigned int* su = (const unsigned int*)&sv;
    float4 bv0 = *reinterpret_cast<const float4*>(bias + c * 8);
    float4 bv1 = *reinterpret_cast<const float4*>(bias + c * 8 + 4);
    const float* bp = (const float*)&bv0;
#pragma unroll
    for (int q = 0; q < 4; ++q) {
        float f0 = __uint_as_float(su[q] << 16);
        float f1 = __uint_as_float(su[q] & 0xffff0000u);
        float b0 = (q < 2) ? bp[2 * q] : ((const float*)&bv1)[2 * (q - 2)];
        float b1 = (q < 2) ? bp[2 * q + 1] : ((const float*)&bv1)[2 * (q - 2) + 1];
        acc[2 * q] = fmaf(d2, f0, acc[2 * q]) + b0;
        acc[2 * q + 1] = fmaf(d2, f1, acc[2 * q + 1]) + b1;
    }
#pragma unroll
    for (int k = 0; k < 8; ++k) acc[k] = fmaxf(acc[k], 0.f);

    if (g == 0) {
        // bf16 store (8 elems = uint4)
        unsigned int pk[4];
#pragma unroll
        for (int q = 0; q < 4; ++q) {
            pk[q] = (unsigned int)f2bfu(acc[2 * q]) | ((unsigned int)f2bfu(acc[2 * q + 1]) << 16);
        }
        *reinterpret_cast<uint4*>(zsl + (size_t)row * 384 + c * 8) =
            *reinterpret_cast<const uint4*>(pk);
    } else if (g == 1) {
        // fp8 plain store (8 bytes)
        uint2 qq;
        qq.x = pk8x4(acc[0], acc[1], acc[2], acc[3]);
        qq.y = pk8x4(acc[4], acc[5], acc[6], acc[7]);
        *reinterpret_cast<uint2*>(zqsl + (size_t)row * 384 + c * 8) = qq;
    } else {
        // fp8 pw-scaled store, split: g2 -> bytes 0-3, g3 -> bytes 4-7
        float4 pv = *reinterpret_cast<const float4*>(pwsl + c * 8 + (g - 2) * 4);
        const float* pp = (const float*)&pv;
        int o = (g - 2) * 4;
        unsigned int w = pk8x4(acc[o] * pp[0] * 8.0f, acc[o + 1] * pp[1] * 8.0f,
                               acc[o + 2] * pp[2] * 8.0f, acc[o + 3] * pp[3] * 8.0f);
        *reinterpret_cast<unsigned int*>(zqwsl + (size_t)row * 384 + c * 8 + o) = w;
    }
}

// ---------- loss: fp8 MFMA diagonal dot; 16 pairs per wave ----------
__global__ __launch_bounds__(256) void loss_mfma_kernel(
    const unsigned char* __restrict__ zq, const unsigned char* __restrict__ zqw,
    const int* __restrict__ pos, const int* __restrict__ neg,
    const float* __restrict__ pb, float* __restrict__ out, int p, float inv_total) {
    __shared__ float red[4];
    int lane = threadIdx.x & 63;
    int wv = threadIdx.x >> 6;
    int pairBase = (blockIdx.x * 4 + wv) * 16;
    float term = 0.f;
    if (pairBase < 2 * p) {
        int m = lane & 15;   // A-row / B-col = pair within wave
        int kg = lane >> 4;  // k-octet
        int pi = pairBase + m;
        int pic = (pi < 2 * p) ? pi : (2 * p - 1);
        bool isneg = (pic >= p);
        const int* pr = isneg ? neg : pos;
        int idx = isneg ? (pic - p) : pic;
        int a = pr[idx];
        int b = pr[p + idx];
        const long* pa = reinterpret_cast<const long*>(zq + (size_t)a * 384) + kg;
        const long* pbw = reinterpret_cast<const long*>(zqw + (size_t)b * 384) + kg;
        f32x4 acc = {0.f, 0.f, 0.f, 0.f};
#pragma unroll
        for (int s = 0; s < 12; ++s) {
            long av = pa[s * 4];
            long bv = pbw[s * 4];
            acc = __builtin_amdgcn_mfma_f32_16x16x32_fp8_fp8(av, bv, acc, 0, 0, 0);
        }
        bool isdiag = (lane >> 4) == ((lane & 15) >> 2);
        int r2 = lane & 3;
        float v = (r2 == 0) ? acc[0] : (r2 == 1) ? acc[1] : (r2 == 2) ? acc[2] : acc[3];
        if (isdiag && pi < 2 * p) {
            float logit = v * 0.125f + pb[0];
            float t = isneg ? logit : -logit;  // softplus argument
            term = (fmaxf(t, 0.f) + log1pf(expf(-fabsf(t)))) * inv_total;
        }
    }
#pragma unroll
    for (int off = 1; off < 64; off <<= 1) term += __shfl_xor(term, off);
    if (lane == 0) red[wv] = term;
    __syncthreads();
    if (threadIdx.x == 0) atomicAdd(out, red[0] + red[1] + red[2] + red[3]);
}

extern "C" void kernel_launch(void* const* d_in, const int* in_sizes, int n_in,
                              void* d_out, int out_size, void* d_ws, size_t ws_size,
                              hipStream_t stream) {
    const float* x      = (const float*)d_in[0];
    const int*   ei     = (const int*)d_in[1];
    const int*   pos    = (const int*)d_in[2];
    const int*   neg    = (const int*)d_in[3];
    const float* gcn_w  = (const float*)d_in[4];
    const float* gcn_b  = (const float*)d_in[5];
    const float* pred_w = (const float*)d_in[6];
    const float* pred_b = (const float*)d_in[7];
    float* out = (float*)d_out;

    const int n = in_sizes[0] / DD;     // 50000
    const int e = in_sizes[1] / 2;      // 640000
    const int p = in_sizes[2] / 2;      // 100000
    const int nb = (n + 255) / 256;

    char* ws = (char*)d_ws;
    size_t off = 0;
    auto alloc = [&](size_t bytes) {
        void* ptr = ws + off;
        off += (bytes + 255) & ~(size_t)255;
        return ptr;
    };
    float* dinv      = (float*)alloc((size_t)n * 4);
    int*   counts    = (int*)alloc((size_t)n * 4);
    int*   rowptr    = (int*)alloc((size_t)(n + 1) * 4);
    int*   cursor    = (int*)alloc((size_t)n * 4);
    int*   partial   = (int*)alloc(256 * 4);
    int*   partial2  = (int*)alloc(256 * 4);
    int*   csr_src   = (int*)alloc((size_t)e * 4);
    float* csr_coef  = (float*)alloc((size_t)e * 4);
    ushort* wfrag    = (ushort*)alloc((size_t)3 * 2048 * 8 * 2);
    ushort* xh = (ushort*)alloc((size_t)n * 128 * 2);
    ushort* hw = (ushort*)alloc((size_t)n * 128 * 2);
    ushort* zh = (ushort*)alloc((size_t)n * 384 * 2);
    unsigned char* zq  = (unsigned char*)alloc((size_t)n * 384);
    unsigned char* zqw = (unsigned char*)alloc((size_t)n * 384);
    (void)ws_size;

    hipMemsetAsync(counts, 0, (size_t)n * 4, stream);
    hipMemsetAsync(d_out, 0, (size_t)out_size * 4, stream);

    count_kernel<<<(e + 255) / 256, 256, 0, stream>>>(counts, ei + e, e);
    dinv_kernel<<<nb, 256, 0, stream>>>(dinv, counts, n);
    scan_blocks<<<nb, 256, 0, stream>>>(counts, rowptr, partial, n);
    scan_partials<<<1, 256, 0, stream>>>(partial, partial2, nb);
    add_offsets<<<nb, 256, 0, stream>>>(rowptr, cursor, partial2, n, e);
    fill_kernel<<<(e + 255) / 256, 256, 0, stream>>>(ei, dinv, cursor, csr_src, csr_coef, e);

    cvt_kernel<<<(int)(((size_t)n * 128 + 255) / 256), 256, 0, stream>>>(
        x, (__hip_bfloat16*)xh, (size_t)n * 128);
    wpack_kernel<<<24, 256, 0, stream>>>(gcn_w, wfrag);

    const int ntiles = n / 16;
    for (int l = 0; l < 3; ++l) {
        const ushort* hsrc = (l == 0) ? xh : (zh + (size_t)(l - 1) * 128);
        int ld = (l == 0) ? 128 : 384;
        gemm_mfma_kernel<<<ntiles, 256, 0, stream>>>(
            hsrc, ld, wfrag + (size_t)l * 2048 * 8, hw, ntiles);
        aggregate_kernel<<<(n * 64 + 255) / 256, 256, 0, stream>>>(
            hw, rowptr, csr_src, csr_coef, dinv, gcn_b + (size_t)l * 128,
            pred_w + (size_t)l * 128,
            zh + (size_t)l * 128, zq + (size_t)l * 128, zqw + (size_t)l * 128, n);
    }

    float inv_total = 1.0f / (2.0f * (float)p);
    int lossWaves = (2 * p + 15) / 16;
    int lossBlocks = (lossWaves + 3) / 4;
    loss_mfma_kernel<<<lossBlocks, 256, 0, stream>>>(
        zq, zqw, pos, neg, pred_b, out, p, inv_total);
}

// Round 8
// 293.761 us; speedup vs baseline: 7.0768x; 1.0293x over previous
//
#include <hip/hip_runtime.h>
#include <hip/hip_bf16.h>

#define DD 128

typedef __attribute__((ext_vector_type(8))) short short8;
typedef __attribute__((ext_vector_type(4))) float f32x4;

static __device__ __forceinline__ int gtid() {
    return blockIdx.x * blockDim.x + threadIdx.x;
}

static __device__ __forceinline__ ushort f2bfu(float f) {
    __hip_bfloat16 h = __float2bfloat16(f);
    return *reinterpret_cast<ushort*>(&h);
}

// ---- fp8 e4m3fn encode (manual fallback, RNE, subnormal-correct) ----
static __device__ __forceinline__ unsigned int fp8e(float f) {
    unsigned int s = (__float_as_uint(f) >> 31) << 7;
    float a = fabsf(f);
    if (a < 0.015625f) return s | (unsigned int)rintf(a * 512.0f);  // subnormal
    unsigned int u = __float_as_uint(a);
    u += 0x0007FFFFu + ((u >> 20) & 1u);           // RNE round mantissa to 3 bits
    unsigned int e8 = (u >> 23) - 120u;
    unsigned int m = (u >> 20) & 7u;
    if (e8 > 15u || (e8 == 15u && m == 7u)) return s | 0x7Eu;  // clamp to 448
    return s | (e8 << 3) | m;
}

// pack 4 f32 -> 4 fp8 bytes (HW cvt when available)
static __device__ __forceinline__ unsigned int pk8x4(float a, float b, float c, float d) {
#if __has_builtin(__builtin_amdgcn_cvt_pk_fp8_f32)
    int v = __builtin_amdgcn_cvt_pk_fp8_f32(a, b, 0, false);
    v = __builtin_amdgcn_cvt_pk_fp8_f32(c, d, v, true);
    return (unsigned int)v;
#else
    return fp8e(a) | (fp8e(b) << 8) | (fp8e(c) << 16) | (fp8e(d) << 24);
#endif
}

// ---------- degree / CSR build ----------

__global__ void count_kernel(int* __restrict__ counts, const int* __restrict__ dst, int e) {
    int i = gtid();
    if (i < e) atomicAdd(&counts[dst[i]], 1);
}

__global__ void dinv_kernel(float* __restrict__ dinv, const int* __restrict__ counts, int n) {
    int i = gtid();
    if (i < n) dinv[i] = rsqrtf(1.0f + (float)counts[i]);
}

__global__ __launch_bounds__(256) void scan_blocks(const int* __restrict__ counts,
                                                   int* __restrict__ rowptr,
                                                   int* __restrict__ partial, int n) {
    __shared__ int s[256];
    int i = blockIdx.x * 256 + threadIdx.x;
    int v = (i < n) ? counts[i] : 0;
    s[threadIdx.x] = v;
    __syncthreads();
    for (int off = 1; off < 256; off <<= 1) {
        int t = (threadIdx.x >= off) ? s[threadIdx.x - off] : 0;
        __syncthreads();
        s[threadIdx.x] += t;
        __syncthreads();
    }
    if (i < n) rowptr[i] = s[threadIdx.x] - v;
    if (threadIdx.x == 255) partial[blockIdx.x] = s[255];
}

__global__ __launch_bounds__(256) void scan_partials(int* __restrict__ partial,
                                                     int* __restrict__ partial2, int nb) {
    __shared__ int s[256];
    int v = (threadIdx.x < nb) ? partial[threadIdx.x] : 0;
    s[threadIdx.x] = v;
    __syncthreads();
    for (int off = 1; off < 256; off <<= 1) {
        int t = (threadIdx.x >= off) ? s[threadIdx.x - off] : 0;
        __syncthreads();
        s[threadIdx.x] += t;
        __syncthreads();
    }
    partial2[threadIdx.x] = s[threadIdx.x] - v;
}

__global__ __launch_bounds__(256) void add_offsets(int* __restrict__ rowptr,
                                                   int* __restrict__ cursor,
                                                   const int* __restrict__ partial2,
                                                   int n, int e) {
    int i = blockIdx.x * 256 + threadIdx.x;
    if (i < n) {
        int r = rowptr[i] + partial2[blockIdx.x];
        rowptr[i] = r;
        cursor[i] = r;
        if (i == n - 1) rowptr[n] = e;
    }
}

__global__ void fill_kernel(const int* __restrict__ ei, const float* __restrict__ dinv,
                            int* __restrict__ cursor, int* __restrict__ csr_src,
                            float* __restrict__ csr_coef, int e) {
    int i = gtid();
    if (i >= e) return;
    int s = ei[i];
    int d = ei[e + i];
    float c = dinv[s] * dinv[d];
    int pos = atomicAdd(&cursor[d], 1);
    csr_src[pos] = s;
    csr_coef[pos] = c;
}

// ---------- x -> bf16 ----------
__global__ void cvt_kernel(const float* __restrict__ x, __hip_bfloat16* __restrict__ xh, size_t m) {
    size_t i = (size_t)blockIdx.x * blockDim.x + threadIdx.x;
    if (i < m) xh[i] = __float2bfloat16(x[i]);
}

// ---------- W -> bf16 MFMA B-fragment order ----------
__global__ __launch_bounds__(256) void wpack_kernel(const float* __restrict__ gcn_w,
                                                    ushort* __restrict__ wfrag) {
    int tid = blockIdx.x * 256 + threadIdx.x;
    if (tid >= 3 * 4 * 8 * 64) return;
    int lane = tid & 63;
    int c = (tid >> 6) & 7;
    int s = (tid >> 9) & 3;
    int l = tid >> 11;
    const float* W = gcn_w + (size_t)l * 128 * 128;
    int col = c * 16 + (lane & 15);
    int k0 = s * 32 + (lane >> 4) * 8;
    ushort u[8];
#pragma unroll
    for (int j = 0; j < 8; ++j) {
        u[j] = f2bfu(W[(size_t)(k0 + j) * 128 + col]);
    }
    *reinterpret_cast<uint4*>(wfrag + (size_t)tid * 8) = *reinterpret_cast<const uint4*>(u);
}

// ---------- MFMA GEMM ----------
__global__ __launch_bounds__(256) void gemm_mfma_kernel(
    const ushort* __restrict__ hsrc, int ld, const ushort* __restrict__ wfrag,
    ushort* __restrict__ out, int ntiles) {
    int lane = threadIdx.x & 63;
    int wv = threadIdx.x >> 6;
    short8 b0[4], b1[4];
    int c0 = wv * 2;
#pragma unroll
    for (int s = 0; s < 4; ++s) {
        b0[s] = *reinterpret_cast<const short8*>(wfrag + ((size_t)(s * 8 + c0) * 64 + lane) * 8);
        b1[s] = *reinterpret_cast<const short8*>(wfrag + ((size_t)(s * 8 + c0 + 1) * 64 + lane) * 8);
    }
    int rlo = lane & 15;
    int kg = lane >> 4;
    for (int rt = blockIdx.x; rt < ntiles; rt += gridDim.x) {
        const ushort* ap = hsrc + (size_t)(rt * 16 + rlo) * ld + kg * 8;
        short8 a0 = *reinterpret_cast<const short8*>(ap);
        short8 a1 = *reinterpret_cast<const short8*>(ap + 32);
        short8 a2 = *reinterpret_cast<const short8*>(ap + 64);
        short8 a3 = *reinterpret_cast<const short8*>(ap + 96);
        f32x4 acc0 = {0.f, 0.f, 0.f, 0.f};
        f32x4 acc1 = {0.f, 0.f, 0.f, 0.f};
        acc0 = __builtin_amdgcn_mfma_f32_16x16x32_bf16(a0, b0[0], acc0, 0, 0, 0);
        acc1 = __builtin_amdgcn_mfma_f32_16x16x32_bf16(a0, b1[0], acc1, 0, 0, 0);
        acc0 = __builtin_amdgcn_mfma_f32_16x16x32_bf16(a1, b0[1], acc0, 0, 0, 0);
        acc1 = __builtin_amdgcn_mfma_f32_16x16x32_bf16(a1, b1[1], acc1, 0, 0, 0);
        acc0 = __builtin_amdgcn_mfma_f32_16x16x32_bf16(a2, b0[2], acc0, 0, 0, 0);
        acc1 = __builtin_amdgcn_mfma_f32_16x16x32_bf16(a2, b1[2], acc1, 0, 0, 0);
        acc0 = __builtin_amdgcn_mfma_f32_16x16x32_bf16(a3, b0[3], acc0, 0, 0, 0);
        acc1 = __builtin_amdgcn_mfma_f32_16x16x32_bf16(a3, b1[3], acc1, 0, 0, 0);
        int row0 = rt * 16 + kg * 4;
        ushort* orow = out + (size_t)row0 * 128 + wv * 32 + rlo;
#pragma unroll
        for (int r = 0; r < 4; ++r) {
            orow[(size_t)r * 128] = f2bfu(acc0[r]);
            orow[(size_t)r * 128 + 16] = f2bfu(acc1[r]);
        }
    }
}

// ---------- fused aggregate + self-loop + bias + relu; bf16 + fp8 + fp8(pw-scaled) outputs ----------
// one wave per dst row; 4 edges in flight (16-lane groups) x2 unroll, uint4 gathers.
__global__ __launch_bounds__(256) void aggregate_kernel(
    const ushort* __restrict__ hw, const int* __restrict__ rowptr,
    const int* __restrict__ csr_src, const float* __restrict__ csr_coef,
    const float* __restrict__ dinv, const float* __restrict__ bias,
    const float* __restrict__ pwsl,
    ushort* __restrict__ zsl, unsigned char* __restrict__ zqsl,
    unsigned char* __restrict__ zqwsl, int n) {
    int gid = gtid();
    int row = gid >> 6;
    if (row >= n) return;
    int lane = threadIdx.x & 63;
    int g = lane >> 4;   // edge sub-group 0..3
    int c = lane & 15;   // feature chunk (8 feats each)
    int j0 = rowptr[row], j1 = rowptr[row + 1];
    float acc[8] = {0.f, 0.f, 0.f, 0.f, 0.f, 0.f, 0.f, 0.f};
    int j = j0 + g;
    // 2-deep unrolled gather loop (8 gathers in flight per wave)
    for (; j + 4 < j1; j += 8) {
        int s0 = csr_src[j];
        float c0 = csr_coef[j];
        int s1 = csr_src[j + 4];
        float c1 = csr_coef[j + 4];
        uint4 v0 = *reinterpret_cast<const uint4*>(hw + (size_t)s0 * 128 + c * 8);
        uint4 v1 = *reinterpret_cast<const uint4*>(hw + (size_t)s1 * 128 + c * 8);
        const unsigned int* u0 = (const unsigned int*)&v0;
        const unsigned int* u1 = (const unsigned int*)&v1;
#pragma unroll
        for (int q = 0; q < 4; ++q) {
            acc[2 * q] = fmaf(c0, __uint_as_float(u0[q] << 16), acc[2 * q]);
            acc[2 * q + 1] = fmaf(c0, __uint_as_float(u0[q] & 0xffff0000u), acc[2 * q + 1]);
        }
#pragma unroll
        for (int q = 0; q < 4; ++q) {
            acc[2 * q] = fmaf(c1, __uint_as_float(u1[q] << 16), acc[2 * q]);
            acc[2 * q + 1] = fmaf(c1, __uint_as_float(u1[q] & 0xffff0000u), acc[2 * q + 1]);
        }
    }
    if (j < j1) {
        int s0 = csr_src[j];
        float c0 = csr_coef[j];
        uint4 v0 = *reinterpret_cast<const uint4*>(hw + (size_t)s0 * 128 + c * 8);
        const unsigned int* u0 = (const unsigned int*)&v0;
#pragma unroll
        for (int q = 0; q < 4; ++q) {
            acc[2 * q] = fmaf(c0, __uint_as_float(u0[q] << 16), acc[2 * q]);
            acc[2 * q + 1] = fmaf(c0, __uint_as_float(u0[q] & 0xffff0000u), acc[2 * q + 1]);
        }
    }
#pragma unroll
    for (int k = 0; k < 8; ++k) {
        acc[k] += __shfl_xor(acc[k], 16);
        acc[k] += __shfl_xor(acc[k], 32);
    }
    // self-loop + bias + relu (all lanes hold full reduced chunk)
    float di = dinv[row];
    float d2 = di * di;
    uint4 sv = *reinterpret_cast<const uint4*>(hw + (size_t)row * 128 + c * 8);
    const unsigned int* su = (const unsigned int*)&sv;
    float4 bv0 = *reinterpret_cast<const float4*>(bias + c * 8);
    float4 bv1 = *reinterpret_cast<const float4*>(bias + c * 8 + 4);
    const float* bp0 = (const float*)&bv0;
    const float* bp1 = (const float*)&bv1;
#pragma unroll
    for (int q = 0; q < 4; ++q) {
        float f0 = __uint_as_float(su[q] << 16);
        float f1 = __uint_as_float(su[q] & 0xffff0000u);
        float b0 = (q < 2) ? bp0[2 * q] : bp1[2 * (q - 2)];
        float b1 = (q < 2) ? bp0[2 * q + 1] : bp1[2 * (q - 2) + 1];
        acc[2 * q] = fmaf(d2, f0, acc[2 * q]) + b0;
        acc[2 * q + 1] = fmaf(d2, f1, acc[2 * q + 1]) + b1;
    }
#pragma unroll
    for (int k = 0; k < 8; ++k) acc[k] = fmaxf(acc[k], 0.f);

    if (g == 0) {
        unsigned int pk[4];
#pragma unroll
        for (int q = 0; q < 4; ++q) {
            pk[q] = (unsigned int)f2bfu(acc[2 * q]) | ((unsigned int)f2bfu(acc[2 * q + 1]) << 16);
        }
        *reinterpret_cast<uint4*>(zsl + (size_t)row * 384 + c * 8) =
            *reinterpret_cast<const uint4*>(pk);
    } else if (g == 1) {
        uint2 qq;
        qq.x = pk8x4(acc[0], acc[1], acc[2], acc[3]);
        qq.y = pk8x4(acc[4], acc[5], acc[6], acc[7]);
        *reinterpret_cast<uint2*>(zqsl + (size_t)row * 384 + c * 8) = qq;
    } else {
        float4 pv = *reinterpret_cast<const float4*>(pwsl + c * 8 + (g - 2) * 4);
        const float* pp = (const float*)&pv;
        int o = (g - 2) * 4;
        unsigned int w = pk8x4(acc[o] * pp[0] * 8.0f, acc[o + 1] * pp[1] * 8.0f,
                               acc[o + 2] * pp[2] * 8.0f, acc[o + 3] * pp[3] * 8.0f);
        *reinterpret_cast<unsigned int*>(zqwsl + (size_t)row * 384 + c * 8 + o) = w;
    }
}

// ---------- loss: fp8 MFMA diagonal dot; 16 pairs per wave; all 24 gathers preloaded ----------
__global__ __launch_bounds__(256) void loss_mfma_kernel(
    const unsigned char* __restrict__ zq, const unsigned char* __restrict__ zqw,
    const int* __restrict__ pos, const int* __restrict__ neg,
    const float* __restrict__ pb, float* __restrict__ out, int p, float inv_total) {
    __shared__ float red[4];
    int lane = threadIdx.x & 63;
    int wv = threadIdx.x >> 6;
    int pairBase = (blockIdx.x * 4 + wv) * 16;
    float term = 0.f;
    if (pairBase < 2 * p) {
        int m = lane & 15;   // pair within wave
        int kg = lane >> 4;  // k-octet
        int pi = pairBase + m;
        int pic = (pi < 2 * p) ? pi : (2 * p - 1);
        bool isneg = (pic >= p);
        const int* pr = isneg ? neg : pos;
        int idx = isneg ? (pic - p) : pic;
        int a = pr[idx];
        int b = pr[p + idx];
        const long* pa = reinterpret_cast<const long*>(zq + (size_t)a * 384) + kg;
        const long* pbw = reinterpret_cast<const long*>(zqw + (size_t)b * 384) + kg;
        // preload ALL fragments (24 outstanding loads) before any MFMA
        long av[12], bv[12];
#pragma unroll
        for (int s = 0; s < 12; ++s) av[s] = pa[s * 4];
#pragma unroll
        for (int s = 0; s < 12; ++s) bv[s] = pbw[s * 4];
        f32x4 acc = {0.f, 0.f, 0.f, 0.f};
#pragma unroll
        for (int s = 0; s < 12; ++s) {
            acc = __builtin_amdgcn_mfma_f32_16x16x32_fp8_fp8(av[s], bv[s], acc, 0, 0, 0);
        }
        bool isdiag = (lane >> 4) == ((lane & 15) >> 2);
        int r2 = lane & 3;
        float v = (r2 == 0) ? acc[0] : (r2 == 1) ? acc[1] : (r2 == 2) ? acc[2] : acc[3];
        if (isdiag && pi < 2 * p) {
            float logit = v * 0.125f + pb[0];
            float t = isneg ? logit : -logit;  // softplus argument
            term = (fmaxf(t, 0.f) + log1pf(expf(-fabsf(t)))) * inv_total;
        }
    }
#pragma unroll
    for (int off = 1; off < 64; off <<= 1) term += __shfl_xor(term, off);
    if (lane == 0) red[wv] = term;
    __syncthreads();
    if (threadIdx.x == 0) atomicAdd(out, red[0] + red[1] + red[2] + red[3]);
}

extern "C" void kernel_launch(void* const* d_in, const int* in_sizes, int n_in,
                              void* d_out, int out_size, void* d_ws, size_t ws_size,
                              hipStream_t stream) {
    const float* x      = (const float*)d_in[0];
    const int*   ei     = (const int*)d_in[1];
    const int*   pos    = (const int*)d_in[2];
    const int*   neg    = (const int*)d_in[3];
    const float* gcn_w  = (const float*)d_in[4];
    const float* gcn_b  = (const float*)d_in[5];
    const float* pred_w = (const float*)d_in[6];
    const float* pred_b = (const float*)d_in[7];
    float* out = (float*)d_out;

    const int n = in_sizes[0] / DD;     // 50000
    const int e = in_sizes[1] / 2;      // 640000
    const int p = in_sizes[2] / 2;      // 100000
    const int nb = (n + 255) / 256;

    char* ws = (char*)d_ws;
    size_t off = 0;
    auto alloc = [&](size_t bytes) {
        void* ptr = ws + off;
        off += (bytes + 255) & ~(size_t)255;
        return ptr;
    };
    float* dinv      = (float*)alloc((size_t)n * 4);
    int*   counts    = (int*)alloc((size_t)n * 4);
    int*   rowptr    = (int*)alloc((size_t)(n + 1) * 4);
    int*   cursor    = (int*)alloc((size_t)n * 4);
    int*   partial   = (int*)alloc(256 * 4);
    int*   partial2  = (int*)alloc(256 * 4);
    int*   csr_src   = (int*)alloc((size_t)e * 4);
    float* csr_coef  = (float*)alloc((size_t)e * 4);
    ushort* wfrag    = (ushort*)alloc((size_t)3 * 2048 * 8 * 2);
    ushort* xh = (ushort*)alloc((size_t)n * 128 * 2);
    ushort* hw = (ushort*)alloc((size_t)n * 128 * 2);
    ushort* zh = (ushort*)alloc((size_t)n * 384 * 2);
    unsigned char* zq  = (unsigned char*)alloc((size_t)n * 384);
    unsigned char* zqw = (unsigned char*)alloc((size_t)n * 384);
    (void)ws_size;

    hipMemsetAsync(counts, 0, (size_t)n * 4, stream);
    hipMemsetAsync(d_out, 0, (size_t)out_size * 4, stream);

    count_kernel<<<(e + 255) / 256, 256, 0, stream>>>(counts, ei + e, e);
    dinv_kernel<<<nb, 256, 0, stream>>>(dinv, counts, n);
    scan_blocks<<<nb, 256, 0, stream>>>(counts, rowptr, partial, n);
    scan_partials<<<1, 256, 0, stream>>>(partial, partial2, nb);
    add_offsets<<<nb, 256, 0, stream>>>(rowptr, cursor, partial2, n, e);
    fill_kernel<<<(e + 255) / 256, 256, 0, stream>>>(ei, dinv, cursor, csr_src, csr_coef, e);

    cvt_kernel<<<(int)(((size_t)n * 128 + 255) / 256), 256, 0, stream>>>(
        x, (__hip_bfloat16*)xh, (size_t)n * 128);
    wpack_kernel<<<24, 256, 0, stream>>>(gcn_w, wfrag);

    const int ntiles = n / 16;
    for (int l = 0; l < 3; ++l) {
        const ushort* hsrc = (l == 0) ? xh : (zh + (size_t)(l - 1) * 128);
        int ld = (l == 0) ? 128 : 384;
        gemm_mfma_kernel<<<ntiles, 256, 0, stream>>>(
            hsrc, ld, wfrag + (size_t)l * 2048 * 8, hw, ntiles);
        aggregate_kernel<<<(n * 64 + 255) / 256, 256, 0, stream>>>(
            hw, rowptr, csr_src, csr_coef, dinv, gcn_b + (size_t)l * 128,
            pred_w + (size_t)l * 128,
            zh + (size_t)l * 128, zq + (size_t)l * 128, zqw + (size_t)l * 128, n);
    }

    float inv_total = 1.0f / (2.0f * (float)p);
    int lossWaves = (2 * p + 15) / 16;
    int lossBlocks = (lossWaves + 3) / 4;
    loss_mfma_kernel<<<lossBlocks, 256, 0, stream>>>(
        zq, zqw, pos, neg, pred_b, out, p, inv_total);
}